// Round 17
// baseline (325.757 us; speedup 1.0000x reference)
//
#include <hip/hip_runtime.h>

#define S_LEN 1024
#define BATCH 8
#define EMB   1024
#define NH    16
#define HD    64
#define FFD   4096
#define ROWS  (S_LEN*BATCH)   // 8192

typedef __attribute__((ext_vector_type(8))) short  short8;
typedef __attribute__((ext_vector_type(4))) float  float4v;
typedef __attribute__((ext_vector_type(4))) unsigned int uint4v;

struct alignas(8) us4 { unsigned short x, y, z, w; };

__device__ __forceinline__ unsigned short f2bf(float f) {
    unsigned int u = __float_as_uint(f);
    u += 0x7fffu + ((u >> 16) & 1u);       // round-to-nearest-even
    return (unsigned short)(u >> 16);
}
__device__ __forceinline__ float bf2f(unsigned short b) {
    return __uint_as_float((unsigned int)b << 16);
}
__device__ __forceinline__ unsigned int cvtpk_bf16(float lo, float hi) {
    unsigned int r;
    asm("v_cvt_pk_bf16_f32 %0, %1, %2" : "=v"(r) : "v"(lo), "v"(hi));
    return r;
}
__device__ __forceinline__ float exp2v(float x) {   // v_exp_f32 = 2^x
    float r;
    asm("v_exp_f32 %0, %1" : "=v"(r) : "v"(x));
    return r;
}

__device__ __forceinline__ void gload_lds16(const void* g, void* l) {
    __builtin_amdgcn_global_load_lds(
        (const __attribute__((address_space(1))) unsigned int*)g,
        (__attribute__((address_space(3))) unsigned int*)l, 16, 0, 0);
}

// LDS byte offset for element-row `row` (128B pitch = 64 bf16) and 16B chunk
// `chunk`, XOR-swizzled so ds_read_b128 phases are conflict-free.
__device__ __forceinline__ int swz(int row, int chunk) {
    return (row << 7) + ((chunk ^ (row & 7)) << 4);
}

// XCD-aware decode (T1): 1-D grid, nwg%8==0, M-panels = 32. Blocks with the
// same m-panel (ly) share id%8 -> same XCD -> A-panel L2-filled once per XCD.
__device__ __forceinline__ void xcd_decode(int id, int& lx, int& ly) {
    int k = id & 7, j = id >> 3;
    ly = k * 4 + (j & 3);
    lx = j >> 2;
}

// ---------------------------------------------------------------- fused cast f32->bf16
__global__ __launch_bounds__(256) void cast_all(const float* __restrict__ s0, unsigned short* __restrict__ d0, int n0,
                                                const float* __restrict__ s1, unsigned short* __restrict__ d1, int n1,
                                                const float* __restrict__ s2, unsigned short* __restrict__ d2, int n2,
                                                const float* __restrict__ s3, unsigned short* __restrict__ d3, int n3,
                                                const float* __restrict__ s4, unsigned short* __restrict__ d4, int n4) {
    int i = blockIdx.x * 256 + threadIdx.x;   // index in float4 units
    const float* s; unsigned short* d;
    if (i < n0)                { s = s0; d = d0; }
    else if ((i -= n0) < n1)   { s = s1; d = d1; }
    else if ((i -= n1) < n2)   { s = s2; d = d2; }
    else if ((i -= n2) < n3)   { s = s3; d = d3; }
    else if ((i -= n3) < n4)   { s = s4; d = d4; }
    else return;
    float4 v = ((const float4*)s)[i];
    us4 o = { f2bf(v.x), f2bf(v.y), f2bf(v.z), f2bf(v.w) };
    ((us4*)d)[i] = o;
}

// ================================================================ 256x256 1-barrier GEMM
// C = A * B^T, bf16 out. The r12-proven 1-barrier counted-vmcnt structure at
// the 256x256 tile: A TRIPLE-buffered (3x32K, slot kt%3, 2-deep prefetch),
// B DOUBLE-buffered (2x32K, slot kt&1, 1-deep) -> 160 KB LDS, 1 block/CU.
// Per K-tile: reads{A-lo 8 + B 8} -> stageB(t+1)+stageA(t+2) -> lgkmcnt ->
// 32 MFMA -> reads{A-hi 8} -> lgkmcnt -> 32 MFMA -> vmcnt(4) -> barrier.
// vmcnt(4) drains B(t+1)+A(t+1) (oldest 8 of 12), leaves A(t+2) in flight.
// WAR: stageB(t+1) overwrites B slot (t-1)&1 and stageA(t+2) overwrites A
// slot (t-1)%3, both drained at iter t-1's lgkmcnts before its end barrier.
// MODE 0: (acc+bias)*(col<EMB?QSCALE:1)   MODE 2: relu(acc+bias)
#define QSCALE 0.18033688011112042f    // 0.125 * log2(e): softmax runs in exp2 units
template <int MODE>
__global__ __launch_bounds__(512, 2) void gemm256d(const unsigned short* __restrict__ A,
                                                   const unsigned short* __restrict__ Bw,
                                                   const float* __restrict__ bias,
                                                   unsigned short* __restrict__ outb,
                                                   int M, int N, int K) {
    __shared__ char lds[163840];   // A: [0,96K) 3x32K; B: [96K,160K) 2x32K
    const int tid = threadIdx.x, lane = tid & 63, w = tid >> 6;
    const int wr = w >> 2, wc = w & 3;     // 2M x 4N, wave owns 128x64
    const int g = lane >> 4, qs = lane & 15;
    int lx, ly;
    xcd_decode(blockIdx.x, lx, ly);
    const int m0 = ly * 256, n0 = lx * 256;
    const int nt = K >> 6;

    size_t baseA[4], baseB[4];
    int ldsOff[4];
#pragma unroll
    for (int q = 0; q < 4; ++q) {
        int ci = q * 512 + tid;
        int row = ci >> 3;                 // 0..255
        int c = (ci & 7) ^ (row & 7);
        baseA[q] = (size_t)(m0 + row) * K + c * 8;
        baseB[q] = (size_t)(n0 + row) * K + c * 8;
        ldsOff[q] = ci * 16;
    }

    auto stageA = [&](int kt) {            // slot kt%3
        int ktc = kt < nt ? kt : 0;        // clamp: garbage lands, never read
        int slot = kt % 3;
#pragma unroll
        for (int q = 0; q < 4; ++q)
            gload_lds16(A + baseA[q] + (size_t)ktc * 64,
                        lds + slot * 32768 + ldsOff[q]);
    };
    auto stageB = [&](int kt) {            // slot kt&1
        int ktc = kt < nt ? kt : 0;
        int slot = kt & 1;
#pragma unroll
        for (int q = 0; q < 4; ++q)
            gload_lds16(Bw + baseB[q] + (size_t)ktc * 64,
                        lds + 98304 + slot * 32768 + ldsOff[q]);
    };

    auto rdA = [&](int slot, int ig, int mk) -> short8 {   // ig 0..7
        int arow = wr * 128 + ig * 16 + qs;
        return *(const short8*)(lds + slot * 32768 + swz(arow, mk * 4 + g));
    };
    auto rdB = [&](int slot, int j, int mk) -> short8 {    // j 0..3
        int brow = wc * 64 + j * 16 + qs;
        return *(const short8*)(lds + 98304 + slot * 32768 + swz(brow, mk * 4 + g));
    };

    float4v acc[8][4];
#pragma unroll
    for (int i = 0; i < 8; ++i)
#pragma unroll
        for (int j = 0; j < 4; ++j) acc[i][j] = (float4v){0.f, 0.f, 0.f, 0.f};

    short8 a[4][2], b[4][2];

    // prologue: A(0), B(0), A(1) = 12 gloads; vmcnt(4) drains A(0),B(0).
    stageA(0); stageB(0); stageA(1);
    asm volatile("s_waitcnt vmcnt(4)" ::: "memory");
    __builtin_amdgcn_s_barrier();

    for (int t = 0; t < nt; ++t) {
        const int sa = t % 3, sb = t & 1;
        // read group 1: A ig0-3 + B j0-3
#pragma unroll
        for (int i = 0; i < 4; ++i) {
            a[i][0] = rdA(sa, i, 0);
            a[i][1] = rdA(sa, i, 1);
        }
#pragma unroll
        for (int j = 0; j < 4; ++j) {
            b[j][0] = rdB(sb, j, 0);
            b[j][1] = rdB(sb, j, 1);
        }
        stageB(t + 1);                     // B 1-deep
        stageA(t + 2);                     // A 2-deep
        asm volatile("s_waitcnt lgkmcnt(0)" ::: "memory");
        __builtin_amdgcn_sched_barrier(0);
        __builtin_amdgcn_s_setprio(1);
#pragma unroll
        for (int i = 0; i < 4; ++i)
#pragma unroll
            for (int j = 0; j < 4; ++j) {
                acc[i][j] = __builtin_amdgcn_mfma_f32_16x16x32_bf16(
                    a[i][0], b[j][0], acc[i][j], 0, 0, 0);
                acc[i][j] = __builtin_amdgcn_mfma_f32_16x16x32_bf16(
                    a[i][1], b[j][1], acc[i][j], 0, 0, 0);
            }
        __builtin_amdgcn_s_setprio(0);
        // read group 2: A ig4-7 (same slot, same wave -> lgkmcnt suffices)
#pragma unroll
        for (int i = 0; i < 4; ++i) {
            a[i][0] = rdA(sa, 4 + i, 0);
            a[i][1] = rdA(sa, 4 + i, 1);
        }
        asm volatile("s_waitcnt lgkmcnt(0)" ::: "memory");
        __builtin_amdgcn_sched_barrier(0);
        __builtin_amdgcn_s_setprio(1);
#pragma unroll
        for (int i = 0; i < 4; ++i)
#pragma unroll
            for (int j = 0; j < 4; ++j) {
                acc[4 + i][j] = __builtin_amdgcn_mfma_f32_16x16x32_bf16(
                    a[i][0], b[j][0], acc[4 + i][j], 0, 0, 0);
                acc[4 + i][j] = __builtin_amdgcn_mfma_f32_16x16x32_bf16(
                    a[i][1], b[j][1], acc[4 + i][j], 0, 0, 0);
            }
        __builtin_amdgcn_s_setprio(0);
        asm volatile("s_waitcnt vmcnt(4)" ::: "memory");
        __builtin_amdgcn_s_barrier();
    }
    asm volatile("s_waitcnt vmcnt(0)" ::: "memory");

#pragma unroll
    for (int mi = 0; mi < 8; ++mi) {
#pragma unroll
        for (int nj = 0; nj < 4; ++nj) {
            int col = n0 + wc * 64 + nj * 16 + qs;
            float bv = bias[col];
#pragma unroll
            for (int r = 0; r < 4; ++r) {
                int row = m0 + wr * 128 + mi * 16 + g * 4 + r;
                size_t idx = (size_t)row * N + col;
                float v = acc[mi][nj][r] + bv;
                if (MODE == 0) {
                    if (col < EMB) v *= QSCALE;
                    outb[idx] = f2bf(v);
                } else {
                    outb[idx] = f2bf(fmaxf(v, 0.f));
                }
            }
        }
    }
}

// ================================================================ 256x128 1-barrier GEMM
// (r12 winner) Triple-buffered LDS, 2-deep prefetch, one barrier + one
// lgkmcnt(0) + one counted vmcnt(6) per K-tile. 4M x 2N, wave owns 64x64.
// MODE 1: res fp32 (out-proj + src)   MODE 3: res bf16 (FF2 + x)
template <int MODE>
__global__ __launch_bounds__(512, 2) void gemm256n(const unsigned short* __restrict__ A,
                                                   const unsigned short* __restrict__ Bw,
                                                   const float* __restrict__ bias,
                                                   const float* __restrict__ res,
                                                   const unsigned short* __restrict__ resb,
                                                   float* __restrict__ outf,
                                                   int M, int N, int K) {
    __shared__ char lds[147456];   // A: [0,96K) 3x32K slots; B: [96K,144K) 3x16K
    const int tid = threadIdx.x, lane = tid & 63, w = tid >> 6;
    const int wr = w >> 1, wc = w & 1;     // 4M x 2N
    int lx, ly;
    xcd_decode(blockIdx.x, lx, ly);
    const int m0 = ly * 256, n0 = lx * 128;
    const int nt = K >> 6;
    const int g = lane >> 4, qs = lane & 15;

    size_t baseA[4], baseB[2];
    int ldsOffA[4], ldsOffB[2];
#pragma unroll
    for (int q = 0; q < 4; ++q) {
        int ci = q * 512 + tid;
        int row = ci >> 3;                 // 0..255
        int c = (ci & 7) ^ (row & 7);
        baseA[q] = (size_t)(m0 + row) * K + c * 8;
        ldsOffA[q] = ci * 16;
    }
#pragma unroll
    for (int q = 0; q < 2; ++q) {
        int ci = q * 512 + tid;
        int row = ci >> 3;                 // 0..127
        int c = (ci & 7) ^ (row & 7);
        baseB[q] = (size_t)(n0 + row) * K + c * 8;
        ldsOffB[q] = ci * 16;
    }

    auto stage = [&](int kt) {
        int ktc = kt < nt ? kt : 0;        // clamp: garbage lands, never read
        int slot = kt % 3;
#pragma unroll
        for (int q = 0; q < 4; ++q)
            gload_lds16(A + baseA[q] + (size_t)ktc * 64,
                        lds + slot * 32768 + ldsOffA[q]);
#pragma unroll
        for (int q = 0; q < 2; ++q)
            gload_lds16(Bw + baseB[q] + (size_t)ktc * 64,
                        lds + 98304 + slot * 16384 + ldsOffB[q]);
    };

    auto rdA = [&](int slot, int i, int mk) -> short8 {
        int arow = wr * 64 + i * 16 + qs;
        return *(const short8*)(lds + slot * 32768 + swz(arow, mk * 4 + g));
    };
    auto rdB = [&](int slot, int j, int mk) -> short8 {
        int brow = wc * 64 + j * 16 + qs;
        return *(const short8*)(lds + 98304 + slot * 16384 + swz(brow, mk * 4 + g));
    };

    float4v acc[4][4];
#pragma unroll
    for (int i = 0; i < 4; ++i)
#pragma unroll
        for (int j = 0; j < 4; ++j) acc[i][j] = (float4v){0.f, 0.f, 0.f, 0.f};

    short8 a[4][2], b[4][2];

    stage(0); stage(1);
    asm volatile("s_waitcnt vmcnt(6)" ::: "memory");
    __builtin_amdgcn_s_barrier();

    for (int t = 0; t < nt; ++t) {
        const int slot = t % 3;
#pragma unroll
        for (int i = 0; i < 4; ++i) {
            a[i][0] = rdA(slot, i, 0);
            a[i][1] = rdA(slot, i, 1);
        }
#pragma unroll
        for (int j = 0; j < 4; ++j) {
            b[j][0] = rdB(slot, j, 0);
            b[j][1] = rdB(slot, j, 1);
        }
        stage(t + 2);                      // 2-deep prefetch into slot (t+2)%3
        asm volatile("s_waitcnt lgkmcnt(0)" ::: "memory");
        __builtin_amdgcn_sched_barrier(0);
        __builtin_amdgcn_s_setprio(1);
#pragma unroll
        for (int i = 0; i < 4; ++i)
#pragma unroll
            for (int j = 0; j < 4; ++j) {
                acc[i][j] = __builtin_amdgcn_mfma_f32_16x16x32_bf16(
                    a[i][0], b[j][0], acc[i][j], 0, 0, 0);
                acc[i][j] = __builtin_amdgcn_mfma_f32_16x16x32_bf16(
                    a[i][1], b[j][1], acc[i][j], 0, 0, 0);
            }
        __builtin_amdgcn_s_setprio(0);
        asm volatile("s_waitcnt vmcnt(6)" ::: "memory");
        __builtin_amdgcn_s_barrier();
    }
    asm volatile("s_waitcnt vmcnt(0)" ::: "memory");

#pragma unroll
    for (int mi = 0; mi < 4; ++mi) {
#pragma unroll
        for (int j = 0; j < 4; ++j) {
            int col = n0 + wc * 64 + j * 16 + qs;
            float bv = bias[col];
#pragma unroll
            for (int r = 0; r < 4; ++r) {
                int row = m0 + wr * 64 + mi * 16 + g * 4 + r;
                size_t idx = (size_t)row * N + col;
                float v = acc[mi][j][r] + bv;
                if (MODE == 1) outf[idx] = v + res[idx];
                else           outf[idx] = v + bf2f(resb[idx]);
            }
        }
    }
}

// ---------------------------------------------------------------- V transpose
__global__ __launch_bounds__(256) void vtrans(const unsigned short* __restrict__ qkv,
                                              unsigned short* __restrict__ vt) {
    const int bh = blockIdx.y, b = bh >> 4, h = bh & 15;
    const int t0 = blockIdx.x * 64;
    const int tid = threadIdx.x;
    __shared__ unsigned short lds[64][72];
#pragma unroll
    for (int rep = 0; rep < 2; ++rep) {
        int slot = rep * 256 + tid;
        int row = slot >> 3, cc = slot & 7;
        const unsigned short* g =
            qkv + ((size_t)(t0 + row) * BATCH + b) * 3072 + 2 * EMB + h * 64 + cc * 8;
        *(uint4v*)&lds[row][cc * 8] = *(const uint4v*)g;
    }
    __syncthreads();
#pragma unroll
    for (int rep = 0; rep < 2; ++rep) {
        int slot = rep * 256 + tid;
        int d = slot >> 3, tc = slot & 7;
        unsigned short tmp[8] __attribute__((aligned(16)));
#pragma unroll
        for (int j = 0; j < 8; ++j) tmp[j] = lds[tc * 8 + j][d];
        unsigned short* g = vt + ((size_t)bh * 64 + d) * S_LEN + t0 + tc * 8;
        *(uint4v*)g = *(const uint4v*)tmp;
    }
}

// ---------------------------------------------------------------- flash attention
// Swapped QK^T, exp2-unit softmax, defer-max THR=8, 24 KiB LDS -> 6 blocks/CU.
__global__ __launch_bounds__(256, 6) void attn(const unsigned short* __restrict__ qkv,
                                               const unsigned short* __restrict__ vt,
                                               unsigned short* __restrict__ ctx) {
    __shared__ char Ks[64 * 128];
    __shared__ char Vs[64 * 128];   // V^T tile: rows d, cols t
    __shared__ char QP[64 * 128];   // Q staging, then Ps[w] = QP + w*2048
    const int tid = threadIdx.x, lane = tid & 63, w = tid >> 6;
    const int bh = blockIdx.x & 127, b = bh >> 4, h = bh & 15;
    const int s0 = (blockIdx.x >> 7) * 64;
    const int g = lane >> 4, qs = lane & 15;

#pragma unroll
    for (int p = 0; p < 2; ++p) {   // Q stage (once)
        int ci = p * 256 + tid;
        int row = ci >> 3, c = (ci & 7) ^ (row & 7);
        gload_lds16(qkv + ((size_t)(s0 + row) * BATCH + b) * 3072 + h * 64 + c * 8,
                    QP + (p * 256 + w * 64) * 16);
    }
    __syncthreads();                // drains vmcnt: Q fully in LDS

    short8 qa0 = *(const short8*)(QP + swz(w * 16 + qs, 0 * 4 + g));
    short8 qa1 = *(const short8*)(QP + swz(w * 16 + qs, 1 * 4 + g));
    asm volatile("s_waitcnt lgkmcnt(0)" ::: "memory");
    __builtin_amdgcn_sched_barrier(0);          // reads complete before P overwrites
    char* Ps = QP + w * 2048;                   // alias: per-wave P scratch

    float4v O[4];
#pragma unroll
    for (int df = 0; df < 4; ++df) O[df] = (float4v){0.f, 0.f, 0.f, 0.f};
    float m_s = -1e30f;
    float l_s = 0.f;

    for (int t0 = 0; t0 < S_LEN; t0 += 64) {
        __syncthreads();
#pragma unroll
        for (int p = 0; p < 2; ++p) {
            int ci = p * 256 + tid;
            int row = ci >> 3, c = (ci & 7) ^ (row & 7);
            gload_lds16(qkv + ((size_t)(t0 + row) * BATCH + b) * 3072 + EMB + h * 64 + c * 8,
                        Ks + (p * 256 + w * 64) * 16);
            gload_lds16(vt + ((size_t)bh * 64 + row) * S_LEN + t0 + c * 8,
                        Vs + (p * 256 + w * 64) * 16);
        }
        __syncthreads();

        float4v Sf[4];
#pragma unroll
        for (int tf = 0; tf < 4; ++tf) Sf[tf] = (float4v){0.f, 0.f, 0.f, 0.f};
#pragma unroll
        for (int tf = 0; tf < 4; ++tf) {
            int kr = tf * 16 + qs;
            short8 kb0 = *(const short8*)(Ks + swz(kr, 0 * 4 + g));
            short8 kb1 = *(const short8*)(Ks + swz(kr, 1 * 4 + g));
            Sf[tf] = __builtin_amdgcn_mfma_f32_16x16x32_bf16(kb0, qa0, Sf[tf], 0, 0, 0);
            Sf[tf] = __builtin_amdgcn_mfma_f32_16x16x32_bf16(kb1, qa1, Sf[tf], 0, 0, 0);
        }

        float mx = fmaxf(fmaxf(Sf[0][0], Sf[0][1]), fmaxf(Sf[0][2], Sf[0][3]));
#pragma unroll
        for (int tf = 1; tf < 4; ++tf)
            mx = fmaxf(mx, fmaxf(fmaxf(Sf[tf][0], Sf[tf][1]),
                                 fmaxf(Sf[tf][2], Sf[tf][3])));
        mx = fmaxf(mx, __shfl_xor(mx, 16));
        mx = fmaxf(mx, __shfl_xor(mx, 32));

        if (!__all(mx - m_s <= 8.0f)) {
            float mnew = fmaxf(m_s, mx);
            float alpha = exp2v(m_s - mnew);
            m_s = mnew;
            l_s *= alpha;
#pragma unroll
            for (int r = 0; r < 4; ++r) {
                float ar = __shfl(alpha, 4 * g + r);
#pragma unroll
                for (int df = 0; df < 4; ++df) O[df][r] *= ar;
            }
        }

        float rs = 0.f;
#pragma unroll
        for (int tf = 0; tf < 4; ++tf) {
            float p0 = exp2v(Sf[tf][0] - m_s);
            float p1 = exp2v(Sf[tf][1] - m_s);
            float p2 = exp2v(Sf[tf][2] - m_s);
            float p3 = exp2v(Sf[tf][3] - m_s);
            rs += (p0 + p1) + (p2 + p3);
            uint2 pk = make_uint2(cvtpk_bf16(p0, p1), cvtpk_bf16(p2, p3));
            *(uint2*)(Ps + (qs << 7) +
                      (((2 * tf + (g >> 1)) ^ (qs & 7)) << 4) + ((g & 1) << 3)) = pk;
        }
        rs += __shfl_xor(rs, 16);
        rs += __shfl_xor(rs, 32);
        l_s += rs;

        asm volatile("s_waitcnt lgkmcnt(0)" ::: "memory");
        __builtin_amdgcn_sched_barrier(0);

#pragma unroll
        for (int mk = 0; mk < 2; ++mk) {
            short8 pa = *(const short8*)(Ps + swz(qs, mk * 4 + g));
#pragma unroll
            for (int df = 0; df < 4; ++df) {
                int vr = df * 16 + qs;
                short8 vb = *(const short8*)(Vs + swz(vr, mk * 4 + g));
                O[df] = __builtin_amdgcn_mfma_f32_16x16x32_bf16(pa, vb, O[df], 0, 0, 0);
            }
        }
    }

    float inv = __builtin_amdgcn_rcpf(l_s);
#pragma unroll
    for (int r = 0; r < 4; ++r) {
        float ir = __shfl(inv, 4 * g + r);
#pragma unroll
        for (int df = 0; df < 4; ++df) {
            int srow = s0 + w * 16 + g * 4 + r;
            int d    = df * 16 + qs;
            ctx[((size_t)srow * BATCH + b) * EMB + h * 64 + d] = f2bf(O[df][r] * ir);
        }
    }
}

// ---------------------------------------------------------------- LayerNorm (row=E)
__global__ __launch_bounds__(256) void ln_ker(const float* __restrict__ y,
                                              const float* __restrict__ g,
                                              const float* __restrict__ bta,
                                              float* __restrict__ xo,
                                              unsigned short* __restrict__ xb) {
    const int row = blockIdx.x, tid = threadIdx.x, lane = tid & 63, w = tid >> 6;
    float4 v = ((const float4*)(y + (size_t)row * EMB))[tid];
    float s = v.x + v.y + v.z + v.w;
    float q = v.x * v.x + v.y * v.y + v.z * v.z + v.w * v.w;
#pragma unroll
    for (int m = 1; m < 64; m <<= 1) {
        s += __shfl_xor(s, m);
        q += __shfl_xor(q, m);
    }
    __shared__ float ps[4], pq[4];
    if (lane == 0) { ps[w] = s; pq[w] = q; }
    __syncthreads();
    s = ps[0] + ps[1] + ps[2] + ps[3];
    q = pq[0] + pq[1] + pq[2] + pq[3];
    float mean = s * (1.f / EMB);
    float var  = q * (1.f / EMB) - mean * mean;
    float rstd = rsqrtf(var + 1e-5f);
    float4 gv = ((const float4*)g)[tid];
    float4 bv = ((const float4*)bta)[tid];
    float4 o;
    o.x = (v.x - mean) * rstd * gv.x + bv.x;
    o.y = (v.y - mean) * rstd * gv.y + bv.y;
    o.z = (v.z - mean) * rstd * gv.z + bv.z;
    o.w = (v.w - mean) * rstd * gv.w + bv.w;
    if (xo) ((float4*)(xo + (size_t)row * EMB))[tid] = o;
    if (xb) {
        us4 ob = { f2bf(o.x), f2bf(o.y), f2bf(o.z), f2bf(o.w) };
        ((us4*)(xb + (size_t)row * EMB))[tid] = ob;
    }
}

// ================================================================ host
// ws layout (MB): [0,24) weights | [24,72) qkvb | [72,88) srcbf/ctxb |
// [88,104) vtb | [24,40) xbf (reuse) | [40,104) hb (reuse). y in d_out.
extern "C" void kernel_launch(void* const* d_in, const int* in_sizes, int n_in,
                              void* d_out, int out_size, void* d_ws, size_t ws_size,
                              hipStream_t stream) {
    (void)in_sizes; (void)n_in; (void)out_size;
    const float* src       = (const float*)d_in[0];
    const float* in_proj_w = (const float*)d_in[1];
    const float* in_proj_b = (const float*)d_in[2];
    const float* out_w     = (const float*)d_in[3];
    const float* out_b     = (const float*)d_in[4];
    const float* ln1_g     = (const float*)d_in[5];
    const float* ln1_b     = (const float*)d_in[6];
    const float* ln2_g     = (const float*)d_in[7];
    const float* ln2_b     = (const float*)d_in[8];
    const float* w1        = (const float*)d_in[9];
    const float* b1        = (const float*)d_in[10];
    const float* w2        = (const float*)d_in[11];
    const float* b2        = (const float*)d_in[12];

    const size_t MB = 1u << 20;
    if (ws_size < 104 * MB) return;

    char* ws = (char*)d_ws;
    unsigned short* wqkvb = (unsigned short*)(ws);
    unsigned short* wob   = (unsigned short*)(ws + 6 * MB);
    unsigned short* w1b   = (unsigned short*)(ws + 8 * MB);
    unsigned short* w2b   = (unsigned short*)(ws + 16 * MB);
    unsigned short* qkvb  = (unsigned short*)(ws + 24 * MB);
    unsigned short* srcbf = (unsigned short*)(ws + 72 * MB);
    unsigned short* vtb   = (unsigned short*)(ws + 88 * MB);
    unsigned short* ctxb  = (unsigned short*)(ws + 72 * MB);
    unsigned short* xbf   = (unsigned short*)(ws + 24 * MB);
    unsigned short* hb    = (unsigned short*)(ws + 40 * MB);
    float*          yout  = (float*)d_out;

    // fused cast: src, in_proj_w, out_w, w1, w2 (counts in float4 units)
    const int c0 = ROWS * EMB / 4;
    const int c1 = 3 * EMB * EMB / 4;
    const int c2 = EMB * EMB / 4;
    const int c3 = FFD * EMB / 4;
    const int c4 = EMB * FFD / 4;
    const int ctot = c0 + c1 + c2 + c3 + c4;
    cast_all<<<ctot / 256, 256, 0, stream>>>(
        src, srcbf, c0, in_proj_w, wqkvb, c1, out_w, wob, c2,
        w1, w1b, c3, w2, w2b, c4);

    // QKV projection (1-barrier 256², XCD-swizzled, q pre-scaled by 0.125*log2e)
    gemm256d<0><<<(3 * EMB / 256) * 32, 512, 0, stream>>>(
        srcbf, wqkvb, in_proj_b, qkvb, ROWS, 3 * EMB, EMB);

    vtrans<<<dim3(S_LEN / 64, BATCH * NH), 256, 0, stream>>>(qkvb, vtb);

    attn<<<(S_LEN / 64) * BATCH * NH, 256, 0, stream>>>(qkvb, vtb, ctxb);

    // out-projection + fp32 src residual -> y1 (in d_out), 256x128 1-barrier
    gemm256n<1><<<(EMB / 128) * 32, 512, 0, stream>>>(
        ctxb, wob, out_b, src, nullptr, yout, ROWS, EMB, EMB);

    ln_ker<<<ROWS, 256, 0, stream>>>(yout, ln1_g, ln1_b, nullptr, xbf);

    // FF1 + ReLU (1-barrier 256², XCD-swizzled)
    gemm256d<2><<<(FFD / 256) * 32, 512, 0, stream>>>(
        xbf, w1b, b1, hb, ROWS, FFD, EMB);

    // FF2 + bf16 x residual -> y2 (in d_out), 256x128 1-barrier, XCD-swizzled
    gemm256n<3><<<(EMB / 128) * 32, 512, 0, stream>>>(
        hb, w2b, b2, nullptr, xbf, yout, ROWS, EMB, FFD);

    ln_ker<<<ROWS, 256, 0, stream>>>(yout, ln2_g, ln2_b, (float*)d_out, nullptr);
}

// Round 18
// 318.937 us; speedup vs baseline: 1.0214x; 1.0214x over previous
//
#include <hip/hip_runtime.h>

#define S_LEN 1024
#define BATCH 8
#define EMB   1024
#define NH    16
#define HD    64
#define FFD   4096
#define ROWS  (S_LEN*BATCH)   // 8192

typedef __attribute__((ext_vector_type(8))) short  short8;
typedef __attribute__((ext_vector_type(4))) float  float4v;
typedef __attribute__((ext_vector_type(4))) unsigned int uint4v;

struct alignas(8) us4 { unsigned short x, y, z, w; };

__device__ __forceinline__ unsigned short f2bf(float f) {
    unsigned int u = __float_as_uint(f);
    u += 0x7fffu + ((u >> 16) & 1u);       // round-to-nearest-even
    return (unsigned short)(u >> 16);
}
__device__ __forceinline__ float bf2f(unsigned short b) {
    return __uint_as_float((unsigned int)b << 16);
}
__device__ __forceinline__ unsigned int cvtpk_bf16(float lo, float hi) {
    unsigned int r;
    asm("v_cvt_pk_bf16_f32 %0, %1, %2" : "=v"(r) : "v"(lo), "v"(hi));
    return r;
}
__device__ __forceinline__ float exp2v(float x) {   // v_exp_f32 = 2^x
    float r;
    asm("v_exp_f32 %0, %1" : "=v"(r) : "v"(x));
    return r;
}

__device__ __forceinline__ void gload_lds16(const void* g, void* l) {
    __builtin_amdgcn_global_load_lds(
        (const __attribute__((address_space(1))) unsigned int*)g,
        (__attribute__((address_space(3))) unsigned int*)l, 16, 0, 0);
}

// LDS byte offset for element-row `row` (128B pitch = 64 bf16) and 16B chunk
// `chunk`, XOR-swizzled so ds_read_b128 phases are conflict-free.
__device__ __forceinline__ int swz(int row, int chunk) {
    return (row << 7) + ((chunk ^ (row & 7)) << 4);
}

// XCD-aware decode (T1): 1-D grid, nwg%8==0, M-panels = 32. Blocks with the
// same m-panel (ly) share id%8 -> same XCD -> A-panel L2-filled once per XCD.
__device__ __forceinline__ void xcd_decode(int id, int& lx, int& ly) {
    int k = id & 7, j = id >> 3;
    ly = k * 4 + (j & 3);
    lx = j >> 2;
}

// ---------------------------------------------------------------- fused cast f32->bf16
__global__ __launch_bounds__(256) void cast_all(const float* __restrict__ s0, unsigned short* __restrict__ d0, int n0,
                                                const float* __restrict__ s1, unsigned short* __restrict__ d1, int n1,
                                                const float* __restrict__ s2, unsigned short* __restrict__ d2, int n2,
                                                const float* __restrict__ s3, unsigned short* __restrict__ d3, int n3,
                                                const float* __restrict__ s4, unsigned short* __restrict__ d4, int n4) {
    int i = blockIdx.x * 256 + threadIdx.x;   // index in float4 units
    const float* s; unsigned short* d;
    if (i < n0)                { s = s0; d = d0; }
    else if ((i -= n0) < n1)   { s = s1; d = d1; }
    else if ((i -= n1) < n2)   { s = s2; d = d2; }
    else if ((i -= n2) < n3)   { s = s3; d = d3; }
    else if ((i -= n3) < n4)   { s = s4; d = d4; }
    else return;
    float4 v = ((const float4*)s)[i];
    us4 o = { f2bf(v.x), f2bf(v.y), f2bf(v.z), f2bf(v.w) };
    ((us4*)d)[i] = o;
}

// ================================================================ 256x256 1-barrier GEMM
// (r17) A triple-buffered (3x32K), B double-buffered (2x32K) -> 160 KB LDS.
// One barrier + 2x lgkmcnt + counted vmcnt(4) per K-tile.
// MODE 0: (acc+bias)*(col<EMB?QSCALE:1)   MODE 2: relu(acc+bias)
#define QSCALE 0.18033688011112042f    // 0.125 * log2(e): softmax runs in exp2 units
template <int MODE>
__global__ __launch_bounds__(512, 2) void gemm256d(const unsigned short* __restrict__ A,
                                                   const unsigned short* __restrict__ Bw,
                                                   const float* __restrict__ bias,
                                                   unsigned short* __restrict__ outb,
                                                   int M, int N, int K) {
    __shared__ char lds[163840];   // A: [0,96K) 3x32K; B: [96K,160K) 2x32K
    const int tid = threadIdx.x, lane = tid & 63, w = tid >> 6;
    const int wr = w >> 2, wc = w & 3;     // 2M x 4N, wave owns 128x64
    const int g = lane >> 4, qs = lane & 15;
    int lx, ly;
    xcd_decode(blockIdx.x, lx, ly);
    const int m0 = ly * 256, n0 = lx * 256;
    const int nt = K >> 6;

    size_t baseA[4], baseB[4];
    int ldsOff[4];
#pragma unroll
    for (int q = 0; q < 4; ++q) {
        int ci = q * 512 + tid;
        int row = ci >> 3;                 // 0..255
        int c = (ci & 7) ^ (row & 7);
        baseA[q] = (size_t)(m0 + row) * K + c * 8;
        baseB[q] = (size_t)(n0 + row) * K + c * 8;
        ldsOff[q] = ci * 16;
    }

    auto stageA = [&](int kt) {            // slot kt%3
        int ktc = kt < nt ? kt : 0;        // clamp: garbage lands, never read
        int slot = kt % 3;
#pragma unroll
        for (int q = 0; q < 4; ++q)
            gload_lds16(A + baseA[q] + (size_t)ktc * 64,
                        lds + slot * 32768 + ldsOff[q]);
    };
    auto stageB = [&](int kt) {            // slot kt&1
        int ktc = kt < nt ? kt : 0;
        int slot = kt & 1;
#pragma unroll
        for (int q = 0; q < 4; ++q)
            gload_lds16(Bw + baseB[q] + (size_t)ktc * 64,
                        lds + 98304 + slot * 32768 + ldsOff[q]);
    };

    auto rdA = [&](int slot, int ig, int mk) -> short8 {   // ig 0..7
        int arow = wr * 128 + ig * 16 + qs;
        return *(const short8*)(lds + slot * 32768 + swz(arow, mk * 4 + g));
    };
    auto rdB = [&](int slot, int j, int mk) -> short8 {    // j 0..3
        int brow = wc * 64 + j * 16 + qs;
        return *(const short8*)(lds + 98304 + slot * 32768 + swz(brow, mk * 4 + g));
    };

    float4v acc[8][4];
#pragma unroll
    for (int i = 0; i < 8; ++i)
#pragma unroll
        for (int j = 0; j < 4; ++j) acc[i][j] = (float4v){0.f, 0.f, 0.f, 0.f};

    short8 a[4][2], b[4][2];

    stageA(0); stageB(0); stageA(1);
    asm volatile("s_waitcnt vmcnt(4)" ::: "memory");
    __builtin_amdgcn_s_barrier();

    for (int t = 0; t < nt; ++t) {
        const int sa = t % 3, sb = t & 1;
#pragma unroll
        for (int i = 0; i < 4; ++i) {
            a[i][0] = rdA(sa, i, 0);
            a[i][1] = rdA(sa, i, 1);
        }
#pragma unroll
        for (int j = 0; j < 4; ++j) {
            b[j][0] = rdB(sb, j, 0);
            b[j][1] = rdB(sb, j, 1);
        }
        stageB(t + 1);
        stageA(t + 2);
        asm volatile("s_waitcnt lgkmcnt(0)" ::: "memory");
        __builtin_amdgcn_sched_barrier(0);
        __builtin_amdgcn_s_setprio(1);
#pragma unroll
        for (int i = 0; i < 4; ++i)
#pragma unroll
            for (int j = 0; j < 4; ++j) {
                acc[i][j] = __builtin_amdgcn_mfma_f32_16x16x32_bf16(
                    a[i][0], b[j][0], acc[i][j], 0, 0, 0);
                acc[i][j] = __builtin_amdgcn_mfma_f32_16x16x32_bf16(
                    a[i][1], b[j][1], acc[i][j], 0, 0, 0);
            }
        __builtin_amdgcn_s_setprio(0);
#pragma unroll
        for (int i = 0; i < 4; ++i) {
            a[i][0] = rdA(sa, 4 + i, 0);
            a[i][1] = rdA(sa, 4 + i, 1);
        }
        asm volatile("s_waitcnt lgkmcnt(0)" ::: "memory");
        __builtin_amdgcn_sched_barrier(0);
        __builtin_amdgcn_s_setprio(1);
#pragma unroll
        for (int i = 0; i < 4; ++i)
#pragma unroll
            for (int j = 0; j < 4; ++j) {
                acc[4 + i][j] = __builtin_amdgcn_mfma_f32_16x16x32_bf16(
                    a[i][0], b[j][0], acc[4 + i][j], 0, 0, 0);
                acc[4 + i][j] = __builtin_amdgcn_mfma_f32_16x16x32_bf16(
                    a[i][1], b[j][1], acc[4 + i][j], 0, 0, 0);
            }
        __builtin_amdgcn_s_setprio(0);
        asm volatile("s_waitcnt vmcnt(4)" ::: "memory");
        __builtin_amdgcn_s_barrier();
    }
    asm volatile("s_waitcnt vmcnt(0)" ::: "memory");

#pragma unroll
    for (int mi = 0; mi < 8; ++mi) {
#pragma unroll
        for (int nj = 0; nj < 4; ++nj) {
            int col = n0 + wc * 64 + nj * 16 + qs;
            float bv = bias[col];
#pragma unroll
            for (int r = 0; r < 4; ++r) {
                int row = m0 + wr * 128 + mi * 16 + g * 4 + r;
                size_t idx = (size_t)row * N + col;
                float v = acc[mi][nj][r] + bv;
                if (MODE == 0) {
                    if (col < EMB) v *= QSCALE;
                    outb[idx] = f2bf(v);
                } else {
                    outb[idx] = f2bf(fmaxf(v, 0.f));
                }
            }
        }
    }
}

// ================================================================ 256x128 1-barrier GEMM
// (r12 winner) Triple-buffered LDS, 2-deep prefetch, one barrier + one
// lgkmcnt(0) + one counted vmcnt(6) per K-tile. 4M x 2N, wave owns 64x64.
// MODE 4: bf16 out = acc+bias+res_f32   (out-proj + src -> y1 bf16)
// MODE 5: bf16 out = acc+bias+res_bf16  (FF2 + x -> y2 bf16)
template <int MODE>
__global__ __launch_bounds__(512, 2) void gemm256n(const unsigned short* __restrict__ A,
                                                   const unsigned short* __restrict__ Bw,
                                                   const float* __restrict__ bias,
                                                   const float* __restrict__ res,
                                                   const unsigned short* __restrict__ resb,
                                                   unsigned short* __restrict__ outb,
                                                   int M, int N, int K) {
    __shared__ char lds[147456];   // A: [0,96K) 3x32K slots; B: [96K,144K) 3x16K
    const int tid = threadIdx.x, lane = tid & 63, w = tid >> 6;
    const int wr = w >> 1, wc = w & 1;     // 4M x 2N
    int lx, ly;
    xcd_decode(blockIdx.x, lx, ly);
    const int m0 = ly * 256, n0 = lx * 128;
    const int nt = K >> 6;
    const int g = lane >> 4, qs = lane & 15;

    size_t baseA[4], baseB[2];
    int ldsOffA[4], ldsOffB[2];
#pragma unroll
    for (int q = 0; q < 4; ++q) {
        int ci = q * 512 + tid;
        int row = ci >> 3;                 // 0..255
        int c = (ci & 7) ^ (row & 7);
        baseA[q] = (size_t)(m0 + row) * K + c * 8;
        ldsOffA[q] = ci * 16;
    }
#pragma unroll
    for (int q = 0; q < 2; ++q) {
        int ci = q * 512 + tid;
        int row = ci >> 3;                 // 0..127
        int c = (ci & 7) ^ (row & 7);
        baseB[q] = (size_t)(n0 + row) * K + c * 8;
        ldsOffB[q] = ci * 16;
    }

    auto stage = [&](int kt) {
        int ktc = kt < nt ? kt : 0;        // clamp: garbage lands, never read
        int slot = kt % 3;
#pragma unroll
        for (int q = 0; q < 4; ++q)
            gload_lds16(A + baseA[q] + (size_t)ktc * 64,
                        lds + slot * 32768 + ldsOffA[q]);
#pragma unroll
        for (int q = 0; q < 2; ++q)
            gload_lds16(Bw + baseB[q] + (size_t)ktc * 64,
                        lds + 98304 + slot * 16384 + ldsOffB[q]);
    };

    auto rdA = [&](int slot, int i, int mk) -> short8 {
        int arow = wr * 64 + i * 16 + qs;
        return *(const short8*)(lds + slot * 32768 + swz(arow, mk * 4 + g));
    };
    auto rdB = [&](int slot, int j, int mk) -> short8 {
        int brow = wc * 64 + j * 16 + qs;
        return *(const short8*)(lds + 98304 + slot * 16384 + swz(brow, mk * 4 + g));
    };

    float4v acc[4][4];
#pragma unroll
    for (int i = 0; i < 4; ++i)
#pragma unroll
        for (int j = 0; j < 4; ++j) acc[i][j] = (float4v){0.f, 0.f, 0.f, 0.f};

    short8 a[4][2], b[4][2];

    stage(0); stage(1);
    asm volatile("s_waitcnt vmcnt(6)" ::: "memory");
    __builtin_amdgcn_s_barrier();

    for (int t = 0; t < nt; ++t) {
        const int slot = t % 3;
#pragma unroll
        for (int i = 0; i < 4; ++i) {
            a[i][0] = rdA(slot, i, 0);
            a[i][1] = rdA(slot, i, 1);
        }
#pragma unroll
        for (int j = 0; j < 4; ++j) {
            b[j][0] = rdB(slot, j, 0);
            b[j][1] = rdB(slot, j, 1);
        }
        stage(t + 2);                      // 2-deep prefetch into slot (t+2)%3
        asm volatile("s_waitcnt lgkmcnt(0)" ::: "memory");
        __builtin_amdgcn_sched_barrier(0);
        __builtin_amdgcn_s_setprio(1);
#pragma unroll
        for (int i = 0; i < 4; ++i)
#pragma unroll
            for (int j = 0; j < 4; ++j) {
                acc[i][j] = __builtin_amdgcn_mfma_f32_16x16x32_bf16(
                    a[i][0], b[j][0], acc[i][j], 0, 0, 0);
                acc[i][j] = __builtin_amdgcn_mfma_f32_16x16x32_bf16(
                    a[i][1], b[j][1], acc[i][j], 0, 0, 0);
            }
        __builtin_amdgcn_s_setprio(0);
        asm volatile("s_waitcnt vmcnt(6)" ::: "memory");
        __builtin_amdgcn_s_barrier();
    }
    asm volatile("s_waitcnt vmcnt(0)" ::: "memory");

#pragma unroll
    for (int mi = 0; mi < 4; ++mi) {
#pragma unroll
        for (int j = 0; j < 4; ++j) {
            int col = n0 + wc * 64 + j * 16 + qs;
            float bv = bias[col];
#pragma unroll
            for (int r = 0; r < 4; ++r) {
                int row = m0 + wr * 64 + mi * 16 + g * 4 + r;
                size_t idx = (size_t)row * N + col;
                float v = acc[mi][j][r] + bv;
                if (MODE == 4) outb[idx] = f2bf(v + res[idx]);
                else           outb[idx] = f2bf(v + bf2f(resb[idx]));
            }
        }
    }
}

// ---------------------------------------------------------------- V transpose
__global__ __launch_bounds__(256) void vtrans(const unsigned short* __restrict__ qkv,
                                              unsigned short* __restrict__ vt) {
    const int bh = blockIdx.y, b = bh >> 4, h = bh & 15;
    const int t0 = blockIdx.x * 64;
    const int tid = threadIdx.x;
    __shared__ unsigned short lds[64][72];
#pragma unroll
    for (int rep = 0; rep < 2; ++rep) {
        int slot = rep * 256 + tid;
        int row = slot >> 3, cc = slot & 7;
        const unsigned short* g =
            qkv + ((size_t)(t0 + row) * BATCH + b) * 3072 + 2 * EMB + h * 64 + cc * 8;
        *(uint4v*)&lds[row][cc * 8] = *(const uint4v*)g;
    }
    __syncthreads();
#pragma unroll
    for (int rep = 0; rep < 2; ++rep) {
        int slot = rep * 256 + tid;
        int d = slot >> 3, tc = slot & 7;
        unsigned short tmp[8] __attribute__((aligned(16)));
#pragma unroll
        for (int j = 0; j < 8; ++j) tmp[j] = lds[tc * 8 + j][d];
        unsigned short* g = vt + ((size_t)bh * 64 + d) * S_LEN + t0 + tc * 8;
        *(uint4v*)g = *(const uint4v*)tmp;
    }
}

// ---------------------------------------------------------------- flash attention
// Swapped QK^T, exp2-unit softmax, defer-max THR=8, 24 KiB LDS -> 6 blocks/CU.
__global__ __launch_bounds__(256, 6) void attn(const unsigned short* __restrict__ qkv,
                                               const unsigned short* __restrict__ vt,
                                               unsigned short* __restrict__ ctx) {
    __shared__ char Ks[64 * 128];
    __shared__ char Vs[64 * 128];   // V^T tile: rows d, cols t
    __shared__ char QP[64 * 128];   // Q staging, then Ps[w] = QP + w*2048
    const int tid = threadIdx.x, lane = tid & 63, w = tid >> 6;
    const int bh = blockIdx.x & 127, b = bh >> 4, h = bh & 15;
    const int s0 = (blockIdx.x >> 7) * 64;
    const int g = lane >> 4, qs = lane & 15;

#pragma unroll
    for (int p = 0; p < 2; ++p) {   // Q stage (once)
        int ci = p * 256 + tid;
        int row = ci >> 3, c = (ci & 7) ^ (row & 7);
        gload_lds16(qkv + ((size_t)(s0 + row) * BATCH + b) * 3072 + h * 64 + c * 8,
                    QP + (p * 256 + w * 64) * 16);
    }
    __syncthreads();                // drains vmcnt: Q fully in LDS

    short8 qa0 = *(const short8*)(QP + swz(w * 16 + qs, 0 * 4 + g));
    short8 qa1 = *(const short8*)(QP + swz(w * 16 + qs, 1 * 4 + g));
    asm volatile("s_waitcnt lgkmcnt(0)" ::: "memory");
    __builtin_amdgcn_sched_barrier(0);          // reads complete before P overwrites
    char* Ps = QP + w * 2048;                   // alias: per-wave P scratch

    float4v O[4];
#pragma unroll
    for (int df = 0; df < 4; ++df) O[df] = (float4v){0.f, 0.f, 0.f, 0.f};
    float m_s = -1e30f;
    float l_s = 0.f;

    for (int t0 = 0; t0 < S_LEN; t0 += 64) {
        __syncthreads();
#pragma unroll
        for (int p = 0; p < 2; ++p) {
            int ci = p * 256 + tid;
            int row = ci >> 3, c = (ci & 7) ^ (row & 7);
            gload_lds16(qkv + ((size_t)(t0 + row) * BATCH + b) * 3072 + EMB + h * 64 + c * 8,
                        Ks + (p * 256 + w * 64) * 16);
            gload_lds16(vt + ((size_t)bh * 64 + row) * S_LEN + t0 + c * 8,
                        Vs + (p * 256 + w * 64) * 16);
        }
        __syncthreads();

        float4v Sf[4];
#pragma unroll
        for (int tf = 0; tf < 4; ++tf) Sf[tf] = (float4v){0.f, 0.f, 0.f, 0.f};
#pragma unroll
        for (int tf = 0; tf < 4; ++tf) {
            int kr = tf * 16 + qs;
            short8 kb0 = *(const short8*)(Ks + swz(kr, 0 * 4 + g));
            short8 kb1 = *(const short8*)(Ks + swz(kr, 1 * 4 + g));
            Sf[tf] = __builtin_amdgcn_mfma_f32_16x16x32_bf16(kb0, qa0, Sf[tf], 0, 0, 0);
            Sf[tf] = __builtin_amdgcn_mfma_f32_16x16x32_bf16(kb1, qa1, Sf[tf], 0, 0, 0);
        }

        float mx = fmaxf(fmaxf(Sf[0][0], Sf[0][1]), fmaxf(Sf[0][2], Sf[0][3]));
#pragma unroll
        for (int tf = 1; tf < 4; ++tf)
            mx = fmaxf(mx, fmaxf(fmaxf(Sf[tf][0], Sf[tf][1]),
                                 fmaxf(Sf[tf][2], Sf[tf][3])));
        mx = fmaxf(mx, __shfl_xor(mx, 16));
        mx = fmaxf(mx, __shfl_xor(mx, 32));

        if (!__all(mx - m_s <= 8.0f)) {
            float mnew = fmaxf(m_s, mx);
            float alpha = exp2v(m_s - mnew);
            m_s = mnew;
            l_s *= alpha;
#pragma unroll
            for (int r = 0; r < 4; ++r) {
                float ar = __shfl(alpha, 4 * g + r);
#pragma unroll
                for (int df = 0; df < 4; ++df) O[df][r] *= ar;
            }
        }

        float rs = 0.f;
#pragma unroll
        for (int tf = 0; tf < 4; ++tf) {
            float p0 = exp2v(Sf[tf][0] - m_s);
            float p1 = exp2v(Sf[tf][1] - m_s);
            float p2 = exp2v(Sf[tf][2] - m_s);
            float p3 = exp2v(Sf[tf][3] - m_s);
            rs += (p0 + p1) + (p2 + p3);
            uint2 pk = make_uint2(cvtpk_bf16(p0, p1), cvtpk_bf16(p2, p3));
            *(uint2*)(Ps + (qs << 7) +
                      (((2 * tf + (g >> 1)) ^ (qs & 7)) << 4) + ((g & 1) << 3)) = pk;
        }
        rs += __shfl_xor(rs, 16);
        rs += __shfl_xor(rs, 32);
        l_s += rs;

        asm volatile("s_waitcnt lgkmcnt(0)" ::: "memory");
        __builtin_amdgcn_sched_barrier(0);

#pragma unroll
        for (int mk = 0; mk < 2; ++mk) {
            short8 pa = *(const short8*)(Ps + swz(qs, mk * 4 + g));
#pragma unroll
            for (int df = 0; df < 4; ++df) {
                int vr = df * 16 + qs;
                short8 vb = *(const short8*)(Vs + swz(vr, mk * 4 + g));
                O[df] = __builtin_amdgcn_mfma_f32_16x16x32_bf16(pa, vb, O[df], 0, 0, 0);
            }
        }
    }

    float inv = __builtin_amdgcn_rcpf(l_s);
#pragma unroll
    for (int r = 0; r < 4; ++r) {
        float ir = __shfl(inv, 4 * g + r);
#pragma unroll
        for (int df = 0; df < 4; ++df) {
            int srow = s0 + w * 16 + g * 4 + r;
            int d    = df * 16 + qs;
            ctx[((size_t)srow * BATCH + b) * EMB + h * 64 + d] = f2bf(O[df][r] * ir);
        }
    }
}

// ---------------------------------------------------------------- LayerNorm (bf16 in)
// y is bf16 (4 elem/thread); writes fp32 xo and/or bf16 xb.
__global__ __launch_bounds__(256) void ln_ker_b(const unsigned short* __restrict__ yb,
                                                const float* __restrict__ g,
                                                const float* __restrict__ bta,
                                                float* __restrict__ xo,
                                                unsigned short* __restrict__ xb) {
    const int row = blockIdx.x, tid = threadIdx.x, lane = tid & 63, w = tid >> 6;
    us4 yv = ((const us4*)(yb + (size_t)row * EMB))[tid];
    float4 v;
    v.x = bf2f(yv.x); v.y = bf2f(yv.y); v.z = bf2f(yv.z); v.w = bf2f(yv.w);
    float s = v.x + v.y + v.z + v.w;
    float q = v.x * v.x + v.y * v.y + v.z * v.z + v.w * v.w;
#pragma unroll
    for (int m = 1; m < 64; m <<= 1) {
        s += __shfl_xor(s, m);
        q += __shfl_xor(q, m);
    }
    __shared__ float ps[4], pq[4];
    if (lane == 0) { ps[w] = s; pq[w] = q; }
    __syncthreads();
    s = ps[0] + ps[1] + ps[2] + ps[3];
    q = pq[0] + pq[1] + pq[2] + pq[3];
    float mean = s * (1.f / EMB);
    float var  = q * (1.f / EMB) - mean * mean;
    float rstd = rsqrtf(var + 1e-5f);
    float4 gv = ((const float4*)g)[tid];
    float4 bv = ((const float4*)bta)[tid];
    float4 o;
    o.x = (v.x - mean) * rstd * gv.x + bv.x;
    o.y = (v.y - mean) * rstd * gv.y + bv.y;
    o.z = (v.z - mean) * rstd * gv.z + bv.z;
    o.w = (v.w - mean) * rstd * gv.w + bv.w;
    if (xo) ((float4*)(xo + (size_t)row * EMB))[tid] = o;
    if (xb) {
        us4 ob = { f2bf(o.x), f2bf(o.y), f2bf(o.z), f2bf(o.w) };
        ((us4*)(xb + (size_t)row * EMB))[tid] = ob;
    }
}

// ================================================================ host
// ws layout (MB), liveness-verified:
//   wqkvb[0,6) wob[6,8) w1b[8,16) w2b[16,24)   (dead: wqkvb/wob/w1b by FF2)
//   qkvb [24,72)  QKV -> attn
//   srcbf[72,88)  cast -> QKV;  ctxb[72,88) attn -> out-proj (srcbf dead)
//   vtb  [88,104) vtrans -> attn;  ybf1[88,104) out-proj -> LN1 (vtb dead)
//   xbf  [24,40)  LN1 -> FF2 (qkvb dead)
//   hb   [40,104) FF1 -> FF2 (ctxb/ybf1 dead by FF1... ybf1 dead after LN1)
//   ybf2 [0,16)   FF2 -> LN2 (wqkvb/wob/w1b dead)
extern "C" void kernel_launch(void* const* d_in, const int* in_sizes, int n_in,
                              void* d_out, int out_size, void* d_ws, size_t ws_size,
                              hipStream_t stream) {
    (void)in_sizes; (void)n_in; (void)out_size;
    const float* src       = (const float*)d_in[0];
    const float* in_proj_w = (const float*)d_in[1];
    const float* in_proj_b = (const float*)d_in[2];
    const float* out_w     = (const float*)d_in[3];
    const float* out_b     = (const float*)d_in[4];
    const float* ln1_g     = (const float*)d_in[5];
    const float* ln1_b     = (const float*)d_in[6];
    const float* ln2_g     = (const float*)d_in[7];
    const float* ln2_b     = (const float*)d_in[8];
    const float* w1        = (const float*)d_in[9];
    const float* b1        = (const float*)d_in[10];
    const float* w2        = (const float*)d_in[11];
    const float* b2        = (const float*)d_in[12];

    const size_t MB = 1u << 20;
    if (ws_size < 104 * MB) return;

    char* ws = (char*)d_ws;
    unsigned short* wqkvb = (unsigned short*)(ws);
    unsigned short* wob   = (unsigned short*)(ws + 6 * MB);
    unsigned short* w1b   = (unsigned short*)(ws + 8 * MB);
    unsigned short* w2b   = (unsigned short*)(ws + 16 * MB);
    unsigned short* qkvb  = (unsigned short*)(ws + 24 * MB);
    unsigned short* srcbf = (unsigned short*)(ws + 72 * MB);
    unsigned short* vtb   = (unsigned short*)(ws + 88 * MB);
    unsigned short* ctxb  = (unsigned short*)(ws + 72 * MB);   // reuse srcbf
    unsigned short* ybf1  = (unsigned short*)(ws + 88 * MB);   // reuse vtb
    unsigned short* xbf   = (unsigned short*)(ws + 24 * MB);   // reuse qkvb
    unsigned short* hb    = (unsigned short*)(ws + 40 * MB);   // reuse rest
    unsigned short* ybf2  = (unsigned short*)(ws);             // reuse dead weights

    // fused cast: src, in_proj_w, out_w, w1, w2 (counts in float4 units)
    const int c0 = ROWS * EMB / 4;
    const int c1 = 3 * EMB * EMB / 4;
    const int c2 = EMB * EMB / 4;
    const int c3 = FFD * EMB / 4;
    const int c4 = EMB * FFD / 4;
    const int ctot = c0 + c1 + c2 + c3 + c4;
    cast_all<<<ctot / 256, 256, 0, stream>>>(
        src, srcbf, c0, in_proj_w, wqkvb, c1, out_w, wob, c2,
        w1, w1b, c3, w2, w2b, c4);

    // QKV projection (1-barrier 256², XCD-swizzled, q pre-scaled by 0.125*log2e)
    gemm256d<0><<<(3 * EMB / 256) * 32, 512, 0, stream>>>(
        srcbf, wqkvb, in_proj_b, qkvb, ROWS, 3 * EMB, EMB);

    vtrans<<<dim3(S_LEN / 64, BATCH * NH), 256, 0, stream>>>(qkvb, vtb);

    attn<<<(S_LEN / 64) * BATCH * NH, 256, 0, stream>>>(qkvb, vtb, ctxb);

    // out-projection + fp32 src residual -> y1 (bf16), 256x128 1-barrier
    gemm256n<4><<<(EMB / 128) * 32, 512, 0, stream>>>(
        ctxb, wob, out_b, src, nullptr, ybf1, ROWS, EMB, EMB);

    // LN1 (bf16 in) -> xbf
    ln_ker_b<<<ROWS, 256, 0, stream>>>(ybf1, ln1_g, ln1_b, nullptr, xbf);

    // FF1 + ReLU (1-barrier 256², XCD-swizzled)
    gemm256d<2><<<(FFD / 256) * 32, 512, 0, stream>>>(
        xbf, w1b, b1, hb, ROWS, FFD, EMB);

    // FF2 + bf16 x residual -> y2 (bf16), 256x128 1-barrier, XCD-swizzled
    gemm256n<5><<<(EMB / 128) * 32, 512, 0, stream>>>(
        hb, w2b, b2, nullptr, xbf, ybf2, ROWS, EMB, FFD);

    // LN2 (bf16 in) -> fp32 d_out
    ln_ker_b<<<ROWS, 256, 0, stream>>>(ybf2, ln2_g, ln2_b, (float*)d_out, nullptr);
}

// Round 19
// 312.233 us; speedup vs baseline: 1.0433x; 1.0215x over previous
//
#include <hip/hip_runtime.h>

#define S_LEN 1024
#define BATCH 8
#define EMB   1024
#define NH    16
#define HD    64
#define FFD   4096
#define ROWS  (S_LEN*BATCH)   // 8192

typedef __attribute__((ext_vector_type(8))) short  short8;
typedef __attribute__((ext_vector_type(4))) float  float4v;
typedef __attribute__((ext_vector_type(4))) unsigned int uint4v;

struct alignas(8) us4 { unsigned short x, y, z, w; };

__device__ __forceinline__ unsigned short f2bf(float f) {
    unsigned int u = __float_as_uint(f);
    u += 0x7fffu + ((u >> 16) & 1u);       // round-to-nearest-even
    return (unsigned short)(u >> 16);
}
__device__ __forceinline__ float bf2f(unsigned short b) {
    return __uint_as_float((unsigned int)b << 16);
}
__device__ __forceinline__ unsigned int cvtpk_bf16(float lo, float hi) {
    unsigned int r;
    asm("v_cvt_pk_bf16_f32 %0, %1, %2" : "=v"(r) : "v"(lo), "v"(hi));
    return r;
}
__device__ __forceinline__ float exp2v(float x) {   // v_exp_f32 = 2^x
    float r;
    asm("v_exp_f32 %0, %1" : "=v"(r) : "v"(x));
    return r;
}

__device__ __forceinline__ void gload_lds16(const void* g, void* l) {
    __builtin_amdgcn_global_load_lds(
        (const __attribute__((address_space(1))) unsigned int*)g,
        (__attribute__((address_space(3))) unsigned int*)l, 16, 0, 0);
}

// LDS byte offset for element-row `row` (128B pitch = 64 bf16) and 16B chunk
// `chunk`, XOR-swizzled so ds_read_b128 phases are conflict-free.
__device__ __forceinline__ int swz(int row, int chunk) {
    return (row << 7) + ((chunk ^ (row & 7)) << 4);
}

// XCD-aware decode (T1): 1-D grid, nwg%8==0, M-panels = 32. Blocks with the
// same m-panel (ly) share id%8 -> same XCD -> A-panel L2-filled once per XCD.
__device__ __forceinline__ void xcd_decode(int id, int& lx, int& ly) {
    int k = id & 7, j = id >> 3;
    ly = k * 4 + (j & 3);
    lx = j >> 2;
}

// ---------------------------------------------------------------- fused cast f32->bf16
__global__ __launch_bounds__(256) void cast_all(const float* __restrict__ s0, unsigned short* __restrict__ d0, int n0,
                                                const float* __restrict__ s1, unsigned short* __restrict__ d1, int n1,
                                                const float* __restrict__ s2, unsigned short* __restrict__ d2, int n2,
                                                const float* __restrict__ s3, unsigned short* __restrict__ d3, int n3,
                                                const float* __restrict__ s4, unsigned short* __restrict__ d4, int n4) {
    int i = blockIdx.x * 256 + threadIdx.x;   // index in float4 units
    const float* s; unsigned short* d;
    if (i < n0)                { s = s0; d = d0; }
    else if ((i -= n0) < n1)   { s = s1; d = d1; }
    else if ((i -= n1) < n2)   { s = s2; d = d2; }
    else if ((i -= n2) < n3)   { s = s3; d = d3; }
    else if ((i -= n3) < n4)   { s = s4; d = d4; }
    else return;
    float4 v = ((const float4*)s)[i];
    us4 o = { f2bf(v.x), f2bf(v.y), f2bf(v.z), f2bf(v.w) };
    ((us4*)d)[i] = o;
}

#define QSCALE 0.18033688011112042f    // 0.125 * log2(e): softmax runs in exp2 units

// ================================================================ 256x192 1-barrier GEMM
// QKV-shaped variant of the r17-proven 1-barrier schedule: N-tile 192 so
// QKV's grid = 16 n x 32 m = 512 blocks = 2 EVEN rounds (256x256 gave 384
// blocks = 1.5 rounds -> 25% idle tail). A triple-buffered (3x32K), B
// double-buffered (2x24K) -> 144 KB LDS, 1 block/CU. Per K-tile: one
// barrier + 2x lgkmcnt + counted vmcnt(4). vmcnt: prologue A0(4)+B0(3)+A1(4)
// = 11 outstanding, vmcnt(4) leaves exactly A1; steady state 4+3+4 = 11,
// vmcnt(4) drains A(t+1)+B(t+1) -- same invariant as gemm256d.
// MODE 0: bf16 out = (acc+bias)*(col<EMB?QSCALE:1)
__global__ __launch_bounds__(512, 2) void gemm256q(const unsigned short* __restrict__ A,
                                                   const unsigned short* __restrict__ Bw,
                                                   const float* __restrict__ bias,
                                                   unsigned short* __restrict__ outb,
                                                   int M, int N, int K) {
    __shared__ char lds[147456];   // A: [0,96K) 3x32K; B: [96K,144K) 2x24K
    const int tid = threadIdx.x, lane = tid & 63, w = tid >> 6;
    const int wr = w >> 2, wc = w & 3;     // 2M x 4N, wave owns 128x48
    const int g = lane >> 4, qs = lane & 15;
    int lx, ly;
    xcd_decode(blockIdx.x, lx, ly);
    const int m0 = ly * 256, n0 = lx * 192;
    const int nt = K >> 6;

    size_t baseA[4], baseB[3];
    int ldsOffA[4], ldsOffB[3];
#pragma unroll
    for (int q = 0; q < 4; ++q) {
        int ci = q * 512 + tid;
        int row = ci >> 3;                 // 0..255
        int c = (ci & 7) ^ (row & 7);
        baseA[q] = (size_t)(m0 + row) * K + c * 8;
        ldsOffA[q] = ci * 16;
    }
#pragma unroll
    for (int q = 0; q < 3; ++q) {
        int ci = q * 512 + tid;
        int row = ci >> 3;                 // 0..191
        int c = (ci & 7) ^ (row & 7);
        baseB[q] = (size_t)(n0 + row) * K + c * 8;
        ldsOffB[q] = ci * 16;
    }

    auto stageA = [&](int kt) {            // slot kt%3, 4 gloads
        int ktc = kt < nt ? kt : 0;        // clamp: garbage lands, never read
        int slot = kt % 3;
#pragma unroll
        for (int q = 0; q < 4; ++q)
            gload_lds16(A + baseA[q] + (size_t)ktc * 64,
                        lds + slot * 32768 + ldsOffA[q]);
    };
    auto stageB = [&](int kt) {            // slot kt&1, 3 gloads
        int ktc = kt < nt ? kt : 0;
        int slot = kt & 1;
#pragma unroll
        for (int q = 0; q < 3; ++q)
            gload_lds16(Bw + baseB[q] + (size_t)ktc * 64,
                        lds + 98304 + slot * 24576 + ldsOffB[q]);
    };

    auto rdA = [&](int slot, int ig, int mk) -> short8 {   // ig 0..7
        int arow = wr * 128 + ig * 16 + qs;
        return *(const short8*)(lds + slot * 32768 + swz(arow, mk * 4 + g));
    };
    auto rdB = [&](int slot, int j, int mk) -> short8 {    // j 0..2
        int brow = wc * 48 + j * 16 + qs;
        return *(const short8*)(lds + 98304 + slot * 24576 + swz(brow, mk * 4 + g));
    };

    float4v acc[8][3];
#pragma unroll
    for (int i = 0; i < 8; ++i)
#pragma unroll
        for (int j = 0; j < 3; ++j) acc[i][j] = (float4v){0.f, 0.f, 0.f, 0.f};

    short8 a[4][2], b[3][2];

    stageA(0); stageB(0); stageA(1);
    asm volatile("s_waitcnt vmcnt(4)" ::: "memory");
    __builtin_amdgcn_s_barrier();

    for (int t = 0; t < nt; ++t) {
        const int sa = t % 3, sb = t & 1;
#pragma unroll
        for (int i = 0; i < 4; ++i) {
            a[i][0] = rdA(sa, i, 0);
            a[i][1] = rdA(sa, i, 1);
        }
#pragma unroll
        for (int j = 0; j < 3; ++j) {
            b[j][0] = rdB(sb, j, 0);
            b[j][1] = rdB(sb, j, 1);
        }
        stageB(t + 1);
        stageA(t + 2);
        asm volatile("s_waitcnt lgkmcnt(0)" ::: "memory");
        __builtin_amdgcn_sched_barrier(0);
        __builtin_amdgcn_s_setprio(1);
#pragma unroll
        for (int i = 0; i < 4; ++i)
#pragma unroll
            for (int j = 0; j < 3; ++j) {
                acc[i][j] = __builtin_amdgcn_mfma_f32_16x16x32_bf16(
                    a[i][0], b[j][0], acc[i][j], 0, 0, 0);
                acc[i][j] = __builtin_amdgcn_mfma_f32_16x16x32_bf16(
                    a[i][1], b[j][1], acc[i][j], 0, 0, 0);
            }
        __builtin_amdgcn_s_setprio(0);
#pragma unroll
        for (int i = 0; i < 4; ++i) {
            a[i][0] = rdA(sa, 4 + i, 0);
            a[i][1] = rdA(sa, 4 + i, 1);
        }
        asm volatile("s_waitcnt lgkmcnt(0)" ::: "memory");
        __builtin_amdgcn_sched_barrier(0);
        __builtin_amdgcn_s_setprio(1);
#pragma unroll
        for (int i = 0; i < 4; ++i)
#pragma unroll
            for (int j = 0; j < 3; ++j) {
                acc[4 + i][j] = __builtin_amdgcn_mfma_f32_16x16x32_bf16(
                    a[i][0], b[j][0], acc[4 + i][j], 0, 0, 0);
                acc[4 + i][j] = __builtin_amdgcn_mfma_f32_16x16x32_bf16(
                    a[i][1], b[j][1], acc[4 + i][j], 0, 0, 0);
            }
        __builtin_amdgcn_s_setprio(0);
        asm volatile("s_waitcnt vmcnt(4)" ::: "memory");
        __builtin_amdgcn_s_barrier();
    }
    asm volatile("s_waitcnt vmcnt(0)" ::: "memory");

#pragma unroll
    for (int mi = 0; mi < 8; ++mi) {
#pragma unroll
        for (int nj = 0; nj < 3; ++nj) {
            int col = n0 + wc * 48 + nj * 16 + qs;
            float bv = bias[col];
#pragma unroll
            for (int r = 0; r < 4; ++r) {
                int row = m0 + wr * 128 + mi * 16 + g * 4 + r;
                size_t idx = (size_t)row * N + col;
                float v = acc[mi][nj][r] + bv;
                if (col < EMB) v *= QSCALE;
                outb[idx] = f2bf(v);
            }
        }
    }
}

// ================================================================ 256x256 1-barrier GEMM
// (r17) A triple-buffered (3x32K), B double-buffered (2x32K) -> 160 KB LDS.
// One barrier + 2x lgkmcnt + counted vmcnt(4) per K-tile.
// MODE 0: (acc+bias)*(col<EMB?QSCALE:1)   MODE 2: relu(acc+bias)
template <int MODE>
__global__ __launch_bounds__(512, 2) void gemm256d(const unsigned short* __restrict__ A,
                                                   const unsigned short* __restrict__ Bw,
                                                   const float* __restrict__ bias,
                                                   unsigned short* __restrict__ outb,
                                                   int M, int N, int K) {
    __shared__ char lds[163840];   // A: [0,96K) 3x32K; B: [96K,160K) 2x32K
    const int tid = threadIdx.x, lane = tid & 63, w = tid >> 6;
    const int wr = w >> 2, wc = w & 3;     // 2M x 4N, wave owns 128x64
    const int g = lane >> 4, qs = lane & 15;
    int lx, ly;
    xcd_decode(blockIdx.x, lx, ly);
    const int m0 = ly * 256, n0 = lx * 256;
    const int nt = K >> 6;

    size_t baseA[4], baseB[4];
    int ldsOff[4];
#pragma unroll
    for (int q = 0; q < 4; ++q) {
        int ci = q * 512 + tid;
        int row = ci >> 3;                 // 0..255
        int c = (ci & 7) ^ (row & 7);
        baseA[q] = (size_t)(m0 + row) * K + c * 8;
        baseB[q] = (size_t)(n0 + row) * K + c * 8;
        ldsOff[q] = ci * 16;
    }

    auto stageA = [&](int kt) {            // slot kt%3
        int ktc = kt < nt ? kt : 0;        // clamp: garbage lands, never read
        int slot = kt % 3;
#pragma unroll
        for (int q = 0; q < 4; ++q)
            gload_lds16(A + baseA[q] + (size_t)ktc * 64,
                        lds + slot * 32768 + ldsOff[q]);
    };
    auto stageB = [&](int kt) {            // slot kt&1
        int ktc = kt < nt ? kt : 0;
        int slot = kt & 1;
#pragma unroll
        for (int q = 0; q < 4; ++q)
            gload_lds16(Bw + baseB[q] + (size_t)ktc * 64,
                        lds + 98304 + slot * 32768 + ldsOff[q]);
    };

    auto rdA = [&](int slot, int ig, int mk) -> short8 {   // ig 0..7
        int arow = wr * 128 + ig * 16 + qs;
        return *(const short8*)(lds + slot * 32768 + swz(arow, mk * 4 + g));
    };
    auto rdB = [&](int slot, int j, int mk) -> short8 {    // j 0..3
        int brow = wc * 64 + j * 16 + qs;
        return *(const short8*)(lds + 98304 + slot * 32768 + swz(brow, mk * 4 + g));
    };

    float4v acc[8][4];
#pragma unroll
    for (int i = 0; i < 8; ++i)
#pragma unroll
        for (int j = 0; j < 4; ++j) acc[i][j] = (float4v){0.f, 0.f, 0.f, 0.f};

    short8 a[4][2], b[4][2];

    stageA(0); stageB(0); stageA(1);
    asm volatile("s_waitcnt vmcnt(4)" ::: "memory");
    __builtin_amdgcn_s_barrier();

    for (int t = 0; t < nt; ++t) {
        const int sa = t % 3, sb = t & 1;
#pragma unroll
        for (int i = 0; i < 4; ++i) {
            a[i][0] = rdA(sa, i, 0);
            a[i][1] = rdA(sa, i, 1);
        }
#pragma unroll
        for (int j = 0; j < 4; ++j) {
            b[j][0] = rdB(sb, j, 0);
            b[j][1] = rdB(sb, j, 1);
        }
        stageB(t + 1);
        stageA(t + 2);
        asm volatile("s_waitcnt lgkmcnt(0)" ::: "memory");
        __builtin_amdgcn_sched_barrier(0);
        __builtin_amdgcn_s_setprio(1);
#pragma unroll
        for (int i = 0; i < 4; ++i)
#pragma unroll
            for (int j = 0; j < 4; ++j) {
                acc[i][j] = __builtin_amdgcn_mfma_f32_16x16x32_bf16(
                    a[i][0], b[j][0], acc[i][j], 0, 0, 0);
                acc[i][j] = __builtin_amdgcn_mfma_f32_16x16x32_bf16(
                    a[i][1], b[j][1], acc[i][j], 0, 0, 0);
            }
        __builtin_amdgcn_s_setprio(0);
#pragma unroll
        for (int i = 0; i < 4; ++i) {
            a[i][0] = rdA(sa, 4 + i, 0);
            a[i][1] = rdA(sa, 4 + i, 1);
        }
        asm volatile("s_waitcnt lgkmcnt(0)" ::: "memory");
        __builtin_amdgcn_sched_barrier(0);
        __builtin_amdgcn_s_setprio(1);
#pragma unroll
        for (int i = 0; i < 4; ++i)
#pragma unroll
            for (int j = 0; j < 4; ++j) {
                acc[4 + i][j] = __builtin_amdgcn_mfma_f32_16x16x32_bf16(
                    a[i][0], b[j][0], acc[4 + i][j], 0, 0, 0);
                acc[4 + i][j] = __builtin_amdgcn_mfma_f32_16x16x32_bf16(
                    a[i][1], b[j][1], acc[4 + i][j], 0, 0, 0);
            }
        __builtin_amdgcn_s_setprio(0);
        asm volatile("s_waitcnt vmcnt(4)" ::: "memory");
        __builtin_amdgcn_s_barrier();
    }
    asm volatile("s_waitcnt vmcnt(0)" ::: "memory");

#pragma unroll
    for (int mi = 0; mi < 8; ++mi) {
#pragma unroll
        for (int nj = 0; nj < 4; ++nj) {
            int col = n0 + wc * 64 + nj * 16 + qs;
            float bv = bias[col];
#pragma unroll
            for (int r = 0; r < 4; ++r) {
                int row = m0 + wr * 128 + mi * 16 + g * 4 + r;
                size_t idx = (size_t)row * N + col;
                float v = acc[mi][nj][r] + bv;
                if (MODE == 0) {
                    if (col < EMB) v *= QSCALE;
                    outb[idx] = f2bf(v);
                } else {
                    outb[idx] = f2bf(fmaxf(v, 0.f));
                }
            }
        }
    }
}

// ================================================================ 256x128 1-barrier GEMM
// (r12 winner) Triple-buffered LDS, 2-deep prefetch, one barrier + one
// lgkmcnt(0) + one counted vmcnt(6) per K-tile. 4M x 2N, wave owns 64x64.
// MODE 4: bf16 out = acc+bias+res_f32   (out-proj + src -> y1 bf16)
// MODE 5: bf16 out = acc+bias+res_bf16  (FF2 + x -> y2 bf16)
template <int MODE>
__global__ __launch_bounds__(512, 2) void gemm256n(const unsigned short* __restrict__ A,
                                                   const unsigned short* __restrict__ Bw,
                                                   const float* __restrict__ bias,
                                                   const float* __restrict__ res,
                                                   const unsigned short* __restrict__ resb,
                                                   unsigned short* __restrict__ outb,
                                                   int M, int N, int K) {
    __shared__ char lds[147456];   // A: [0,96K) 3x32K slots; B: [96K,144K) 3x16K
    const int tid = threadIdx.x, lane = tid & 63, w = tid >> 6;
    const int wr = w >> 1, wc = w & 1;     // 4M x 2N
    int lx, ly;
    xcd_decode(blockIdx.x, lx, ly);
    const int m0 = ly * 256, n0 = lx * 128;
    const int nt = K >> 6;
    const int g = lane >> 4, qs = lane & 15;

    size_t baseA[4], baseB[2];
    int ldsOffA[4], ldsOffB[2];
#pragma unroll
    for (int q = 0; q < 4; ++q) {
        int ci = q * 512 + tid;
        int row = ci >> 3;                 // 0..255
        int c = (ci & 7) ^ (row & 7);
        baseA[q] = (size_t)(m0 + row) * K + c * 8;
        ldsOffA[q] = ci * 16;
    }
#pragma unroll
    for (int q = 0; q < 2; ++q) {
        int ci = q * 512 + tid;
        int row = ci >> 3;                 // 0..127
        int c = (ci & 7) ^ (row & 7);
        baseB[q] = (size_t)(n0 + row) * K + c * 8;
        ldsOffB[q] = ci * 16;
    }

    auto stage = [&](int kt) {
        int ktc = kt < nt ? kt : 0;        // clamp: garbage lands, never read
        int slot = kt % 3;
#pragma unroll
        for (int q = 0; q < 4; ++q)
            gload_lds16(A + baseA[q] + (size_t)ktc * 64,
                        lds + slot * 32768 + ldsOffA[q]);
#pragma unroll
        for (int q = 0; q < 2; ++q)
            gload_lds16(Bw + baseB[q] + (size_t)ktc * 64,
                        lds + 98304 + slot * 16384 + ldsOffB[q]);
    };

    auto rdA = [&](int slot, int i, int mk) -> short8 {
        int arow = wr * 64 + i * 16 + qs;
        return *(const short8*)(lds + slot * 32768 + swz(arow, mk * 4 + g));
    };
    auto rdB = [&](int slot, int j, int mk) -> short8 {
        int brow = wc * 64 + j * 16 + qs;
        return *(const short8*)(lds + 98304 + slot * 16384 + swz(brow, mk * 4 + g));
    };

    float4v acc[4][4];
#pragma unroll
    for (int i = 0; i < 4; ++i)
#pragma unroll
        for (int j = 0; j < 4; ++j) acc[i][j] = (float4v){0.f, 0.f, 0.f, 0.f};

    short8 a[4][2], b[4][2];

    stage(0); stage(1);
    asm volatile("s_waitcnt vmcnt(6)" ::: "memory");
    __builtin_amdgcn_s_barrier();

    for (int t = 0; t < nt; ++t) {
        const int slot = t % 3;
#pragma unroll
        for (int i = 0; i < 4; ++i) {
            a[i][0] = rdA(slot, i, 0);
            a[i][1] = rdA(slot, i, 1);
        }
#pragma unroll
        for (int j = 0; j < 4; ++j) {
            b[j][0] = rdB(slot, j, 0);
            b[j][1] = rdB(slot, j, 1);
        }
        stage(t + 2);                      // 2-deep prefetch into slot (t+2)%3
        asm volatile("s_waitcnt lgkmcnt(0)" ::: "memory");
        __builtin_amdgcn_sched_barrier(0);
        __builtin_amdgcn_s_setprio(1);
#pragma unroll
        for (int i = 0; i < 4; ++i)
#pragma unroll
            for (int j = 0; j < 4; ++j) {
                acc[i][j] = __builtin_amdgcn_mfma_f32_16x16x32_bf16(
                    a[i][0], b[j][0], acc[i][j], 0, 0, 0);
                acc[i][j] = __builtin_amdgcn_mfma_f32_16x16x32_bf16(
                    a[i][1], b[j][1], acc[i][j], 0, 0, 0);
            }
        __builtin_amdgcn_s_setprio(0);
        asm volatile("s_waitcnt vmcnt(6)" ::: "memory");
        __builtin_amdgcn_s_barrier();
    }
    asm volatile("s_waitcnt vmcnt(0)" ::: "memory");

#pragma unroll
    for (int mi = 0; mi < 4; ++mi) {
#pragma unroll
        for (int j = 0; j < 4; ++j) {
            int col = n0 + wc * 64 + j * 16 + qs;
            float bv = bias[col];
#pragma unroll
            for (int r = 0; r < 4; ++r) {
                int row = m0 + wr * 64 + mi * 16 + g * 4 + r;
                size_t idx = (size_t)row * N + col;
                float v = acc[mi][j][r] + bv;
                if (MODE == 4) outb[idx] = f2bf(v + res[idx]);
                else           outb[idx] = f2bf(v + bf2f(resb[idx]));
            }
        }
    }
}

// ---------------------------------------------------------------- V transpose
__global__ __launch_bounds__(256) void vtrans(const unsigned short* __restrict__ qkv,
                                              unsigned short* __restrict__ vt) {
    const int bh = blockIdx.y, b = bh >> 4, h = bh & 15;
    const int t0 = blockIdx.x * 64;
    const int tid = threadIdx.x;
    __shared__ unsigned short lds[64][72];
#pragma unroll
    for (int rep = 0; rep < 2; ++rep) {
        int slot = rep * 256 + tid;
        int row = slot >> 3, cc = slot & 7;
        const unsigned short* g =
            qkv + ((size_t)(t0 + row) * BATCH + b) * 3072 + 2 * EMB + h * 64 + cc * 8;
        *(uint4v*)&lds[row][cc * 8] = *(const uint4v*)g;
    }
    __syncthreads();
#pragma unroll
    for (int rep = 0; rep < 2; ++rep) {
        int slot = rep * 256 + tid;
        int d = slot >> 3, tc = slot & 7;
        unsigned short tmp[8] __attribute__((aligned(16)));
#pragma unroll
        for (int j = 0; j < 8; ++j) tmp[j] = lds[tc * 8 + j][d];
        unsigned short* g = vt + ((size_t)bh * 64 + d) * S_LEN + t0 + tc * 8;
        *(uint4v*)g = *(const uint4v*)tmp;
    }
}

// ---------------------------------------------------------------- flash attention
// Swapped QK^T, exp2-unit softmax, defer-max THR=8, 24 KiB LDS -> 6 blocks/CU.
__global__ __launch_bounds__(256, 6) void attn(const unsigned short* __restrict__ qkv,
                                               const unsigned short* __restrict__ vt,
                                               unsigned short* __restrict__ ctx) {
    __shared__ char Ks[64 * 128];
    __shared__ char Vs[64 * 128];   // V^T tile: rows d, cols t
    __shared__ char QP[64 * 128];   // Q staging, then Ps[w] = QP + w*2048
    const int tid = threadIdx.x, lane = tid & 63, w = tid >> 6;
    const int bh = blockIdx.x & 127, b = bh >> 4, h = bh & 15;
    const int s0 = (blockIdx.x >> 7) * 64;
    const int g = lane >> 4, qs = lane & 15;

#pragma unroll
    for (int p = 0; p < 2; ++p) {   // Q stage (once)
        int ci = p * 256 + tid;
        int row = ci >> 3, c = (ci & 7) ^ (row & 7);
        gload_lds16(qkv + ((size_t)(s0 + row) * BATCH + b) * 3072 + h * 64 + c * 8,
                    QP + (p * 256 + w * 64) * 16);
    }
    __syncthreads();                // drains vmcnt: Q fully in LDS

    short8 qa0 = *(const short8*)(QP + swz(w * 16 + qs, 0 * 4 + g));
    short8 qa1 = *(const short8*)(QP + swz(w * 16 + qs, 1 * 4 + g));
    asm volatile("s_waitcnt lgkmcnt(0)" ::: "memory");
    __builtin_amdgcn_sched_barrier(0);          // reads complete before P overwrites
    char* Ps = QP + w * 2048;                   // alias: per-wave P scratch

    float4v O[4];
#pragma unroll
    for (int df = 0; df < 4; ++df) O[df] = (float4v){0.f, 0.f, 0.f, 0.f};
    float m_s = -1e30f;
    float l_s = 0.f;

    for (int t0 = 0; t0 < S_LEN; t0 += 64) {
        __syncthreads();
#pragma unroll
        for (int p = 0; p < 2; ++p) {
            int ci = p * 256 + tid;
            int row = ci >> 3, c = (ci & 7) ^ (row & 7);
            gload_lds16(qkv + ((size_t)(t0 + row) * BATCH + b) * 3072 + EMB + h * 64 + c * 8,
                        Ks + (p * 256 + w * 64) * 16);
            gload_lds16(vt + ((size_t)bh * 64 + row) * S_LEN + t0 + c * 8,
                        Vs + (p * 256 + w * 64) * 16);
        }
        __syncthreads();

        float4v Sf[4];
#pragma unroll
        for (int tf = 0; tf < 4; ++tf) Sf[tf] = (float4v){0.f, 0.f, 0.f, 0.f};
#pragma unroll
        for (int tf = 0; tf < 4; ++tf) {
            int kr = tf * 16 + qs;
            short8 kb0 = *(const short8*)(Ks + swz(kr, 0 * 4 + g));
            short8 kb1 = *(const short8*)(Ks + swz(kr, 1 * 4 + g));
            Sf[tf] = __builtin_amdgcn_mfma_f32_16x16x32_bf16(kb0, qa0, Sf[tf], 0, 0, 0);
            Sf[tf] = __builtin_amdgcn_mfma_f32_16x16x32_bf16(kb1, qa1, Sf[tf], 0, 0, 0);
        }

        float mx = fmaxf(fmaxf(Sf[0][0], Sf[0][1]), fmaxf(Sf[0][2], Sf[0][3]));
#pragma unroll
        for (int tf = 1; tf < 4; ++tf)
            mx = fmaxf(mx, fmaxf(fmaxf(Sf[tf][0], Sf[tf][1]),
                                 fmaxf(Sf[tf][2], Sf[tf][3])));
        mx = fmaxf(mx, __shfl_xor(mx, 16));
        mx = fmaxf(mx, __shfl_xor(mx, 32));

        if (!__all(mx - m_s <= 8.0f)) {
            float mnew = fmaxf(m_s, mx);
            float alpha = exp2v(m_s - mnew);
            m_s = mnew;
            l_s *= alpha;
#pragma unroll
            for (int r = 0; r < 4; ++r) {
                float ar = __shfl(alpha, 4 * g + r);
#pragma unroll
                for (int df = 0; df < 4; ++df) O[df][r] *= ar;
            }
        }

        float rs = 0.f;
#pragma unroll
        for (int tf = 0; tf < 4; ++tf) {
            float p0 = exp2v(Sf[tf][0] - m_s);
            float p1 = exp2v(Sf[tf][1] - m_s);
            float p2 = exp2v(Sf[tf][2] - m_s);
            float p3 = exp2v(Sf[tf][3] - m_s);
            rs += (p0 + p1) + (p2 + p3);
            uint2 pk = make_uint2(cvtpk_bf16(p0, p1), cvtpk_bf16(p2, p3));
            *(uint2*)(Ps + (qs << 7) +
                      (((2 * tf + (g >> 1)) ^ (qs & 7)) << 4) + ((g & 1) << 3)) = pk;
        }
        rs += __shfl_xor(rs, 16);
        rs += __shfl_xor(rs, 32);
        l_s += rs;

        asm volatile("s_waitcnt lgkmcnt(0)" ::: "memory");
        __builtin_amdgcn_sched_barrier(0);

#pragma unroll
        for (int mk = 0; mk < 2; ++mk) {
            short8 pa = *(const short8*)(Ps + swz(qs, mk * 4 + g));
#pragma unroll
            for (int df = 0; df < 4; ++df) {
                int vr = df * 16 + qs;
                short8 vb = *(const short8*)(Vs + swz(vr, mk * 4 + g));
                O[df] = __builtin_amdgcn_mfma_f32_16x16x32_bf16(pa, vb, O[df], 0, 0, 0);
            }
        }
    }

    float inv = __builtin_amdgcn_rcpf(l_s);
#pragma unroll
    for (int r = 0; r < 4; ++r) {
        float ir = __shfl(inv, 4 * g + r);
#pragma unroll
        for (int df = 0; df < 4; ++df) {
            int srow = s0 + w * 16 + g * 4 + r;
            int d    = df * 16 + qs;
            ctx[((size_t)srow * BATCH + b) * EMB + h * 64 + d] = f2bf(O[df][r] * ir);
        }
    }
}

// ---------------------------------------------------------------- LayerNorm (bf16 in)
__global__ __launch_bounds__(256) void ln_ker_b(const unsigned short* __restrict__ yb,
                                                const float* __restrict__ g,
                                                const float* __restrict__ bta,
                                                float* __restrict__ xo,
                                                unsigned short* __restrict__ xb) {
    const int row = blockIdx.x, tid = threadIdx.x, lane = tid & 63, w = tid >> 6;
    us4 yv = ((const us4*)(yb + (size_t)row * EMB))[tid];
    float4 v;
    v.x = bf2f(yv.x); v.y = bf2f(yv.y); v.z = bf2f(yv.z); v.w = bf2f(yv.w);
    float s = v.x + v.y + v.z + v.w;
    float q = v.x * v.x + v.y * v.y + v.z * v.z + v.w * v.w;
#pragma unroll
    for (int m = 1; m < 64; m <<= 1) {
        s += __shfl_xor(s, m);
        q += __shfl_xor(q, m);
    }
    __shared__ float ps[4], pq[4];
    if (lane == 0) { ps[w] = s; pq[w] = q; }
    __syncthreads();
    s = ps[0] + ps[1] + ps[2] + ps[3];
    q = pq[0] + pq[1] + pq[2] + pq[3];
    float mean = s * (1.f / EMB);
    float var  = q * (1.f / EMB) - mean * mean;
    float rstd = rsqrtf(var + 1e-5f);
    float4 gv = ((const float4*)g)[tid];
    float4 bv = ((const float4*)bta)[tid];
    float4 o;
    o.x = (v.x - mean) * rstd * gv.x + bv.x;
    o.y = (v.y - mean) * rstd * gv.y + bv.y;
    o.z = (v.z - mean) * rstd * gv.z + bv.z;
    o.w = (v.w - mean) * rstd * gv.w + bv.w;
    if (xo) ((float4*)(xo + (size_t)row * EMB))[tid] = o;
    if (xb) {
        us4 ob = { f2bf(o.x), f2bf(o.y), f2bf(o.z), f2bf(o.w) };
        ((us4*)(xb + (size_t)row * EMB))[tid] = ob;
    }
}

// ================================================================ host
// ws layout (MB), liveness-verified (r18):
//   wqkvb[0,6) wob[6,8) w1b[8,16) w2b[16,24)   (dead: wqkvb/wob/w1b by FF2)
//   qkvb [24,72)  QKV -> attn
//   srcbf[72,88)  cast -> QKV;  ctxb[72,88) attn -> out-proj (srcbf dead)
//   vtb  [88,104) vtrans -> attn;  ybf1[88,104) out-proj -> LN1 (vtb dead)
//   xbf  [24,40)  LN1 -> FF2 (qkvb dead)
//   hb   [40,104) FF1 -> FF2
//   ybf2 [0,16)   FF2 -> LN2 (dead weights)
extern "C" void kernel_launch(void* const* d_in, const int* in_sizes, int n_in,
                              void* d_out, int out_size, void* d_ws, size_t ws_size,
                              hipStream_t stream) {
    (void)in_sizes; (void)n_in; (void)out_size;
    const float* src       = (const float*)d_in[0];
    const float* in_proj_w = (const float*)d_in[1];
    const float* in_proj_b = (const float*)d_in[2];
    const float* out_w     = (const float*)d_in[3];
    const float* out_b     = (const float*)d_in[4];
    const float* ln1_g     = (const float*)d_in[5];
    const float* ln1_b     = (const float*)d_in[6];
    const float* ln2_g     = (const float*)d_in[7];
    const float* ln2_b     = (const float*)d_in[8];
    const float* w1        = (const float*)d_in[9];
    const float* b1        = (const float*)d_in[10];
    const float* w2        = (const float*)d_in[11];
    const float* b2        = (const float*)d_in[12];

    const size_t MB = 1u << 20;
    if (ws_size < 104 * MB) return;

    char* ws = (char*)d_ws;
    unsigned short* wqkvb = (unsigned short*)(ws);
    unsigned short* wob   = (unsigned short*)(ws + 6 * MB);
    unsigned short* w1b   = (unsigned short*)(ws + 8 * MB);
    unsigned short* w2b   = (unsigned short*)(ws + 16 * MB);
    unsigned short* qkvb  = (unsigned short*)(ws + 24 * MB);
    unsigned short* srcbf = (unsigned short*)(ws + 72 * MB);
    unsigned short* vtb   = (unsigned short*)(ws + 88 * MB);
    unsigned short* ctxb  = (unsigned short*)(ws + 72 * MB);   // reuse srcbf
    unsigned short* ybf1  = (unsigned short*)(ws + 88 * MB);   // reuse vtb
    unsigned short* xbf   = (unsigned short*)(ws + 24 * MB);   // reuse qkvb
    unsigned short* hb    = (unsigned short*)(ws + 40 * MB);   // reuse rest
    unsigned short* ybf2  = (unsigned short*)(ws);             // reuse dead weights

    // fused cast: src, in_proj_w, out_w, w1, w2 (counts in float4 units)
    const int c0 = ROWS * EMB / 4;
    const int c1 = 3 * EMB * EMB / 4;
    const int c2 = EMB * EMB / 4;
    const int c3 = FFD * EMB / 4;
    const int c4 = EMB * FFD / 4;
    const int ctot = c0 + c1 + c2 + c3 + c4;
    cast_all<<<ctot / 256, 256, 0, stream>>>(
        src, srcbf, c0, in_proj_w, wqkvb, c1, out_w, wob, c2,
        w1, w1b, c3, w2, w2b, c4);

    // QKV projection (1-barrier 256x192, 512 blocks = 2 even rounds,
    // XCD-swizzled, q pre-scaled by 0.125*log2e)
    gemm256q<<<(3 * EMB / 192) * 32, 512, 0, stream>>>(
        srcbf, wqkvb, in_proj_b, qkvb, ROWS, 3 * EMB, EMB);

    vtrans<<<dim3(S_LEN / 64, BATCH * NH), 256, 0, stream>>>(qkvb, vtb);

    attn<<<(S_LEN / 64) * BATCH * NH, 256, 0, stream>>>(qkvb, vtb, ctxb);

    // out-projection + fp32 src residual -> y1 (bf16), 256x128 1-barrier
    gemm256n<4><<<(EMB / 128) * 32, 512, 0, stream>>>(
        ctxb, wob, out_b, src, nullptr, ybf1, ROWS, EMB, EMB);

    // LN1 (bf16 in) -> xbf
    ln_ker_b<<<ROWS, 256, 0, stream>>>(ybf1, ln1_g, ln1_b, nullptr, xbf);

    // FF1 + ReLU (1-barrier 256², XCD-swizzled)
    gemm256d<2><<<(FFD / 256) * 32, 512, 0, stream>>>(
        xbf, w1b, b1, hb, ROWS, FFD, EMB);

    // FF2 + bf16 x residual -> y2 (bf16), 256x128 1-barrier, XCD-swizzled
    gemm256n<5><<<(EMB / 128) * 32, 512, 0, stream>>>(
        hb, w2b, b2, nullptr, xbf, ybf2, ROWS, EMB, FFD);

    // LN2 (bf16 in) -> fp32 d_out
    ln_ker_b<<<ROWS, 256, 0, stream>>>(ybf2, ln2_g, ln2_b, (float*)d_out, nullptr);
}

// Round 20
// 311.698 us; speedup vs baseline: 1.0451x; 1.0017x over previous
//
#include <hip/hip_runtime.h>

#define S_LEN 1024
#define BATCH 8
#define EMB   1024
#define NH    16
#define HD    64
#define FFD   4096
#define ROWS  (S_LEN*BATCH)   // 8192

typedef __attribute__((ext_vector_type(8))) short  short8;
typedef __attribute__((ext_vector_type(4))) float  float4v;
typedef __attribute__((ext_vector_type(4))) unsigned int uint4v;

struct alignas(8) us4 { unsigned short x, y, z, w; };

__device__ __forceinline__ unsigned short f2bf(float f) {
    unsigned int u = __float_as_uint(f);
    u += 0x7fffu + ((u >> 16) & 1u);       // round-to-nearest-even
    return (unsigned short)(u >> 16);
}
__device__ __forceinline__ float bf2f(unsigned short b) {
    return __uint_as_float((unsigned int)b << 16);
}
__device__ __forceinline__ unsigned int cvtpk_bf16(float lo, float hi) {
    unsigned int r;
    asm("v_cvt_pk_bf16_f32 %0, %1, %2" : "=v"(r) : "v"(lo), "v"(hi));
    return r;
}
__device__ __forceinline__ float exp2v(float x) {   // v_exp_f32 = 2^x
    float r;
    asm("v_exp_f32 %0, %1" : "=v"(r) : "v"(x));
    return r;
}

__device__ __forceinline__ void gload_lds16(const void* g, void* l) {
    __builtin_amdgcn_global_load_lds(
        (const __attribute__((address_space(1))) unsigned int*)g,
        (__attribute__((address_space(3))) unsigned int*)l, 16, 0, 0);
}

// LDS byte offset for element-row `row` (128B pitch = 64 bf16) and 16B chunk
// `chunk`, XOR-swizzled so ds_read_b128 phases are conflict-free.
__device__ __forceinline__ int swz(int row, int chunk) {
    return (row << 7) + ((chunk ^ (row & 7)) << 4);
}

// XCD-aware decode (T1): 1-D grid, nwg%8==0, M-panels = 32. Blocks with the
// same m-panel (ly) share id%8 -> same XCD -> A-panel L2-filled once per XCD.
__device__ __forceinline__ void xcd_decode(int id, int& lx, int& ly) {
    int k = id & 7, j = id >> 3;
    ly = k * 4 + (j & 3);
    lx = j >> 2;
}

// ---------------------------------------------------------------- fused cast f32->bf16
__global__ __launch_bounds__(256) void cast_all(const float* __restrict__ s0, unsigned short* __restrict__ d0, int n0,
                                                const float* __restrict__ s1, unsigned short* __restrict__ d1, int n1,
                                                const float* __restrict__ s2, unsigned short* __restrict__ d2, int n2,
                                                const float* __restrict__ s3, unsigned short* __restrict__ d3, int n3,
                                                const float* __restrict__ s4, unsigned short* __restrict__ d4, int n4) {
    int i = blockIdx.x * 256 + threadIdx.x;   // index in float4 units
    const float* s; unsigned short* d;
    if (i < n0)                { s = s0; d = d0; }
    else if ((i -= n0) < n1)   { s = s1; d = d1; }
    else if ((i -= n1) < n2)   { s = s2; d = d2; }
    else if ((i -= n2) < n3)   { s = s3; d = d3; }
    else if ((i -= n3) < n4)   { s = s4; d = d4; }
    else return;
    float4 v = ((const float4*)s)[i];
    us4 o = { f2bf(v.x), f2bf(v.y), f2bf(v.z), f2bf(v.w) };
    ((us4*)d)[i] = o;
}

#define QSCALE 0.18033688011112042f    // 0.125 * log2(e): softmax runs in exp2 units

// ================================================================ 256x192 1-barrier GEMM
// (r19) QKV: grid 512 = 2 even rounds. A 3x32K, B 2x24K = 144 KB.
__global__ __launch_bounds__(512, 2) void gemm256q(const unsigned short* __restrict__ A,
                                                   const unsigned short* __restrict__ Bw,
                                                   const float* __restrict__ bias,
                                                   unsigned short* __restrict__ outb,
                                                   int M, int N, int K) {
    __shared__ char lds[147456];   // A: [0,96K) 3x32K; B: [96K,144K) 2x24K
    const int tid = threadIdx.x, lane = tid & 63, w = tid >> 6;
    const int wr = w >> 2, wc = w & 3;     // 2M x 4N, wave owns 128x48
    const int g = lane >> 4, qs = lane & 15;
    int lx, ly;
    xcd_decode(blockIdx.x, lx, ly);
    const int m0 = ly * 256, n0 = lx * 192;
    const int nt = K >> 6;

    size_t baseA[4], baseB[3];
    int ldsOffA[4], ldsOffB[3];
#pragma unroll
    for (int q = 0; q < 4; ++q) {
        int ci = q * 512 + tid;
        int row = ci >> 3;                 // 0..255
        int c = (ci & 7) ^ (row & 7);
        baseA[q] = (size_t)(m0 + row) * K + c * 8;
        ldsOffA[q] = ci * 16;
    }
#pragma unroll
    for (int q = 0; q < 3; ++q) {
        int ci = q * 512 + tid;
        int row = ci >> 3;                 // 0..191
        int c = (ci & 7) ^ (row & 7);
        baseB[q] = (size_t)(n0 + row) * K + c * 8;
        ldsOffB[q] = ci * 16;
    }

    auto stageA = [&](int kt) {            // slot kt%3, 4 gloads
        int ktc = kt < nt ? kt : 0;        // clamp: garbage lands, never read
        int slot = kt % 3;
#pragma unroll
        for (int q = 0; q < 4; ++q)
            gload_lds16(A + baseA[q] + (size_t)ktc * 64,
                        lds + slot * 32768 + ldsOffA[q]);
    };
    auto stageB = [&](int kt) {            // slot kt&1, 3 gloads
        int ktc = kt < nt ? kt : 0;
        int slot = kt & 1;
#pragma unroll
        for (int q = 0; q < 3; ++q)
            gload_lds16(Bw + baseB[q] + (size_t)ktc * 64,
                        lds + 98304 + slot * 24576 + ldsOffB[q]);
    };

    auto rdA = [&](int slot, int ig, int mk) -> short8 {   // ig 0..7
        int arow = wr * 128 + ig * 16 + qs;
        return *(const short8*)(lds + slot * 32768 + swz(arow, mk * 4 + g));
    };
    auto rdB = [&](int slot, int j, int mk) -> short8 {    // j 0..2
        int brow = wc * 48 + j * 16 + qs;
        return *(const short8*)(lds + 98304 + slot * 24576 + swz(brow, mk * 4 + g));
    };

    float4v acc[8][3];
#pragma unroll
    for (int i = 0; i < 8; ++i)
#pragma unroll
        for (int j = 0; j < 3; ++j) acc[i][j] = (float4v){0.f, 0.f, 0.f, 0.f};

    short8 a[4][2], b[3][2];

    stageA(0); stageB(0); stageA(1);
    asm volatile("s_waitcnt vmcnt(4)" ::: "memory");
    __builtin_amdgcn_s_barrier();

    for (int t = 0; t < nt; ++t) {
        const int sa = t % 3, sb = t & 1;
#pragma unroll
        for (int i = 0; i < 4; ++i) {
            a[i][0] = rdA(sa, i, 0);
            a[i][1] = rdA(sa, i, 1);
        }
#pragma unroll
        for (int j = 0; j < 3; ++j) {
            b[j][0] = rdB(sb, j, 0);
            b[j][1] = rdB(sb, j, 1);
        }
        stageB(t + 1);
        stageA(t + 2);
        asm volatile("s_waitcnt lgkmcnt(0)" ::: "memory");
        __builtin_amdgcn_sched_barrier(0);
        __builtin_amdgcn_s_setprio(1);
#pragma unroll
        for (int i = 0; i < 4; ++i)
#pragma unroll
            for (int j = 0; j < 3; ++j) {
                acc[i][j] = __builtin_amdgcn_mfma_f32_16x16x32_bf16(
                    a[i][0], b[j][0], acc[i][j], 0, 0, 0);
                acc[i][j] = __builtin_amdgcn_mfma_f32_16x16x32_bf16(
                    a[i][1], b[j][1], acc[i][j], 0, 0, 0);
            }
        __builtin_amdgcn_s_setprio(0);
#pragma unroll
        for (int i = 0; i < 4; ++i) {
            a[i][0] = rdA(sa, 4 + i, 0);
            a[i][1] = rdA(sa, 4 + i, 1);
        }
        asm volatile("s_waitcnt lgkmcnt(0)" ::: "memory");
        __builtin_amdgcn_sched_barrier(0);
        __builtin_amdgcn_s_setprio(1);
#pragma unroll
        for (int i = 0; i < 4; ++i)
#pragma unroll
            for (int j = 0; j < 3; ++j) {
                acc[4 + i][j] = __builtin_amdgcn_mfma_f32_16x16x32_bf16(
                    a[i][0], b[j][0], acc[4 + i][j], 0, 0, 0);
                acc[4 + i][j] = __builtin_amdgcn_mfma_f32_16x16x32_bf16(
                    a[i][1], b[j][1], acc[4 + i][j], 0, 0, 0);
            }
        __builtin_amdgcn_s_setprio(0);
        asm volatile("s_waitcnt vmcnt(4)" ::: "memory");
        __builtin_amdgcn_s_barrier();
    }
    asm volatile("s_waitcnt vmcnt(0)" ::: "memory");

#pragma unroll
    for (int mi = 0; mi < 8; ++mi) {
#pragma unroll
        for (int nj = 0; nj < 3; ++nj) {
            int col = n0 + wc * 48 + nj * 16 + qs;
            float bv = bias[col];
#pragma unroll
            for (int r = 0; r < 4; ++r) {
                int row = m0 + wr * 128 + mi * 16 + g * 4 + r;
                size_t idx = (size_t)row * N + col;
                float v = acc[mi][nj][r] + bv;
                if (col < EMB) v *= QSCALE;
                outb[idx] = f2bf(v);
            }
        }
    }
}

// ================================================================ 256x256 1-barrier GEMM
// (r17) A 3x32K, B 2x32K = 160 KB. MODE 0: QKV-scale  MODE 2: relu
template <int MODE>
__global__ __launch_bounds__(512, 2) void gemm256d(const unsigned short* __restrict__ A,
                                                   const unsigned short* __restrict__ Bw,
                                                   const float* __restrict__ bias,
                                                   unsigned short* __restrict__ outb,
                                                   int M, int N, int K) {
    __shared__ char lds[163840];   // A: [0,96K) 3x32K; B: [96K,160K) 2x32K
    const int tid = threadIdx.x, lane = tid & 63, w = tid >> 6;
    const int wr = w >> 2, wc = w & 3;     // 2M x 4N, wave owns 128x64
    const int g = lane >> 4, qs = lane & 15;
    int lx, ly;
    xcd_decode(blockIdx.x, lx, ly);
    const int m0 = ly * 256, n0 = lx * 256;
    const int nt = K >> 6;

    size_t baseA[4], baseB[4];
    int ldsOff[4];
#pragma unroll
    for (int q = 0; q < 4; ++q) {
        int ci = q * 512 + tid;
        int row = ci >> 3;                 // 0..255
        int c = (ci & 7) ^ (row & 7);
        baseA[q] = (size_t)(m0 + row) * K + c * 8;
        baseB[q] = (size_t)(n0 + row) * K + c * 8;
        ldsOff[q] = ci * 16;
    }

    auto stageA = [&](int kt) {            // slot kt%3
        int ktc = kt < nt ? kt : 0;        // clamp: garbage lands, never read
        int slot = kt % 3;
#pragma unroll
        for (int q = 0; q < 4; ++q)
            gload_lds16(A + baseA[q] + (size_t)ktc * 64,
                        lds + slot * 32768 + ldsOff[q]);
    };
    auto stageB = [&](int kt) {            // slot kt&1
        int ktc = kt < nt ? kt : 0;
        int slot = kt & 1;
#pragma unroll
        for (int q = 0; q < 4; ++q)
            gload_lds16(Bw + baseB[q] + (size_t)ktc * 64,
                        lds + 98304 + slot * 32768 + ldsOff[q]);
    };

    auto rdA = [&](int slot, int ig, int mk) -> short8 {   // ig 0..7
        int arow = wr * 128 + ig * 16 + qs;
        return *(const short8*)(lds + slot * 32768 + swz(arow, mk * 4 + g));
    };
    auto rdB = [&](int slot, int j, int mk) -> short8 {    // j 0..3
        int brow = wc * 64 + j * 16 + qs;
        return *(const short8*)(lds + 98304 + slot * 32768 + swz(brow, mk * 4 + g));
    };

    float4v acc[8][4];
#pragma unroll
    for (int i = 0; i < 8; ++i)
#pragma unroll
        for (int j = 0; j < 4; ++j) acc[i][j] = (float4v){0.f, 0.f, 0.f, 0.f};

    short8 a[4][2], b[4][2];

    stageA(0); stageB(0); stageA(1);
    asm volatile("s_waitcnt vmcnt(4)" ::: "memory");
    __builtin_amdgcn_s_barrier();

    for (int t = 0; t < nt; ++t) {
        const int sa = t % 3, sb = t & 1;
#pragma unroll
        for (int i = 0; i < 4; ++i) {
            a[i][0] = rdA(sa, i, 0);
            a[i][1] = rdA(sa, i, 1);
        }
#pragma unroll
        for (int j = 0; j < 4; ++j) {
            b[j][0] = rdB(sb, j, 0);
            b[j][1] = rdB(sb, j, 1);
        }
        stageB(t + 1);
        stageA(t + 2);
        asm volatile("s_waitcnt lgkmcnt(0)" ::: "memory");
        __builtin_amdgcn_sched_barrier(0);
        __builtin_amdgcn_s_setprio(1);
#pragma unroll
        for (int i = 0; i < 4; ++i)
#pragma unroll
            for (int j = 0; j < 4; ++j) {
                acc[i][j] = __builtin_amdgcn_mfma_f32_16x16x32_bf16(
                    a[i][0], b[j][0], acc[i][j], 0, 0, 0);
                acc[i][j] = __builtin_amdgcn_mfma_f32_16x16x32_bf16(
                    a[i][1], b[j][1], acc[i][j], 0, 0, 0);
            }
        __builtin_amdgcn_s_setprio(0);
#pragma unroll
        for (int i = 0; i < 4; ++i) {
            a[i][0] = rdA(sa, 4 + i, 0);
            a[i][1] = rdA(sa, 4 + i, 1);
        }
        asm volatile("s_waitcnt lgkmcnt(0)" ::: "memory");
        __builtin_amdgcn_sched_barrier(0);
        __builtin_amdgcn_s_setprio(1);
#pragma unroll
        for (int i = 0; i < 4; ++i)
#pragma unroll
            for (int j = 0; j < 4; ++j) {
                acc[4 + i][j] = __builtin_amdgcn_mfma_f32_16x16x32_bf16(
                    a[i][0], b[j][0], acc[4 + i][j], 0, 0, 0);
                acc[4 + i][j] = __builtin_amdgcn_mfma_f32_16x16x32_bf16(
                    a[i][1], b[j][1], acc[4 + i][j], 0, 0, 0);
            }
        __builtin_amdgcn_s_setprio(0);
        asm volatile("s_waitcnt vmcnt(4)" ::: "memory");
        __builtin_amdgcn_s_barrier();
    }
    asm volatile("s_waitcnt vmcnt(0)" ::: "memory");

#pragma unroll
    for (int mi = 0; mi < 8; ++mi) {
#pragma unroll
        for (int nj = 0; nj < 4; ++nj) {
            int col = n0 + wc * 64 + nj * 16 + qs;
            float bv = bias[col];
#pragma unroll
            for (int r = 0; r < 4; ++r) {
                int row = m0 + wr * 128 + mi * 16 + g * 4 + r;
                size_t idx = (size_t)row * N + col;
                float v = acc[mi][nj][r] + bv;
                if (MODE == 0) {
                    if (col < EMB) v *= QSCALE;
                    outb[idx] = f2bf(v);
                } else {
                    outb[idx] = f2bf(fmaxf(v, 0.f));
                }
            }
        }
    }
}

// ================================================================ 256x128 1-barrier GEMM
// (r12 winner) MODE 4: bf16 = acc+bias+res_f32   MODE 5: bf16 = acc+bias+res_bf16
template <int MODE>
__global__ __launch_bounds__(512, 2) void gemm256n(const unsigned short* __restrict__ A,
                                                   const unsigned short* __restrict__ Bw,
                                                   const float* __restrict__ bias,
                                                   const float* __restrict__ res,
                                                   const unsigned short* __restrict__ resb,
                                                   unsigned short* __restrict__ outb,
                                                   int M, int N, int K) {
    __shared__ char lds[147456];   // A: [0,96K) 3x32K slots; B: [96K,144K) 3x16K
    const int tid = threadIdx.x, lane = tid & 63, w = tid >> 6;
    const int wr = w >> 1, wc = w & 1;     // 4M x 2N
    int lx, ly;
    xcd_decode(blockIdx.x, lx, ly);
    const int m0 = ly * 256, n0 = lx * 128;
    const int nt = K >> 6;
    const int g = lane >> 4, qs = lane & 15;

    size_t baseA[4], baseB[2];
    int ldsOffA[4], ldsOffB[2];
#pragma unroll
    for (int q = 0; q < 4; ++q) {
        int ci = q * 512 + tid;
        int row = ci >> 3;                 // 0..255
        int c = (ci & 7) ^ (row & 7);
        baseA[q] = (size_t)(m0 + row) * K + c * 8;
        ldsOffA[q] = ci * 16;
    }
#pragma unroll
    for (int q = 0; q < 2; ++q) {
        int ci = q * 512 + tid;
        int row = ci >> 3;                 // 0..127
        int c = (ci & 7) ^ (row & 7);
        baseB[q] = (size_t)(n0 + row) * K + c * 8;
        ldsOffB[q] = ci * 16;
    }

    auto stage = [&](int kt) {
        int ktc = kt < nt ? kt : 0;        // clamp: garbage lands, never read
        int slot = kt % 3;
#pragma unroll
        for (int q = 0; q < 4; ++q)
            gload_lds16(A + baseA[q] + (size_t)ktc * 64,
                        lds + slot * 32768 + ldsOffA[q]);
#pragma unroll
        for (int q = 0; q < 2; ++q)
            gload_lds16(Bw + baseB[q] + (size_t)ktc * 64,
                        lds + 98304 + slot * 16384 + ldsOffB[q]);
    };

    auto rdA = [&](int slot, int i, int mk) -> short8 {
        int arow = wr * 64 + i * 16 + qs;
        return *(const short8*)(lds + slot * 32768 + swz(arow, mk * 4 + g));
    };
    auto rdB = [&](int slot, int j, int mk) -> short8 {
        int brow = wc * 64 + j * 16 + qs;
        return *(const short8*)(lds + 98304 + slot * 16384 + swz(brow, mk * 4 + g));
    };

    float4v acc[4][4];
#pragma unroll
    for (int i = 0; i < 4; ++i)
#pragma unroll
        for (int j = 0; j < 4; ++j) acc[i][j] = (float4v){0.f, 0.f, 0.f, 0.f};

    short8 a[4][2], b[4][2];

    stage(0); stage(1);
    asm volatile("s_waitcnt vmcnt(6)" ::: "memory");
    __builtin_amdgcn_s_barrier();

    for (int t = 0; t < nt; ++t) {
        const int slot = t % 3;
#pragma unroll
        for (int i = 0; i < 4; ++i) {
            a[i][0] = rdA(slot, i, 0);
            a[i][1] = rdA(slot, i, 1);
        }
#pragma unroll
        for (int j = 0; j < 4; ++j) {
            b[j][0] = rdB(slot, j, 0);
            b[j][1] = rdB(slot, j, 1);
        }
        stage(t + 2);                      // 2-deep prefetch into slot (t+2)%3
        asm volatile("s_waitcnt lgkmcnt(0)" ::: "memory");
        __builtin_amdgcn_sched_barrier(0);
        __builtin_amdgcn_s_setprio(1);
#pragma unroll
        for (int i = 0; i < 4; ++i)
#pragma unroll
            for (int j = 0; j < 4; ++j) {
                acc[i][j] = __builtin_amdgcn_mfma_f32_16x16x32_bf16(
                    a[i][0], b[j][0], acc[i][j], 0, 0, 0);
                acc[i][j] = __builtin_amdgcn_mfma_f32_16x16x32_bf16(
                    a[i][1], b[j][1], acc[i][j], 0, 0, 0);
            }
        __builtin_amdgcn_s_setprio(0);
        asm volatile("s_waitcnt vmcnt(6)" ::: "memory");
        __builtin_amdgcn_s_barrier();
    }
    asm volatile("s_waitcnt vmcnt(0)" ::: "memory");

#pragma unroll
    for (int mi = 0; mi < 4; ++mi) {
#pragma unroll
        for (int j = 0; j < 4; ++j) {
            int col = n0 + wc * 64 + j * 16 + qs;
            float bv = bias[col];
#pragma unroll
            for (int r = 0; r < 4; ++r) {
                int row = m0 + wr * 64 + mi * 16 + g * 4 + r;
                size_t idx = (size_t)row * N + col;
                float v = acc[mi][j][r] + bv;
                if (MODE == 4) outb[idx] = f2bf(v + res[idx]);
                else           outb[idx] = f2bf(v + bf2f(resb[idx]));
            }
        }
    }
}

// ---------------------------------------------------------------- V transpose
__global__ __launch_bounds__(256) void vtrans(const unsigned short* __restrict__ qkv,
                                              unsigned short* __restrict__ vt) {
    const int bh = blockIdx.y, b = bh >> 4, h = bh & 15;
    const int t0 = blockIdx.x * 64;
    const int tid = threadIdx.x;
    __shared__ unsigned short lds[64][72];
#pragma unroll
    for (int rep = 0; rep < 2; ++rep) {
        int slot = rep * 256 + tid;
        int row = slot >> 3, cc = slot & 7;
        const unsigned short* g =
            qkv + ((size_t)(t0 + row) * BATCH + b) * 3072 + 2 * EMB + h * 64 + cc * 8;
        *(uint4v*)&lds[row][cc * 8] = *(const uint4v*)g;
    }
    __syncthreads();
#pragma unroll
    for (int rep = 0; rep < 2; ++rep) {
        int slot = rep * 256 + tid;
        int d = slot >> 3, tc = slot & 7;
        unsigned short tmp[8] __attribute__((aligned(16)));
#pragma unroll
        for (int j = 0; j < 8; ++j) tmp[j] = lds[tc * 8 + j][d];
        unsigned short* g = vt + ((size_t)bh * 64 + d) * S_LEN + t0 + tc * 8;
        *(uint4v*)g = *(const uint4v*)tmp;
    }
}

// ---------------------------------------------------------------- flash attention
// Swapped QK^T, exp2-unit softmax, defer-max THR=8, 24 KiB LDS -> 6 blocks/CU.
// Row-sum via ones-column MFMA (O[4] accumulates P-rowsum; rescaled with O).
__global__ __launch_bounds__(256, 6) void attn(const unsigned short* __restrict__ qkv,
                                               const unsigned short* __restrict__ vt,
                                               unsigned short* __restrict__ ctx) {
    __shared__ char Ks[64 * 128];
    __shared__ char Vs[64 * 128];   // V^T tile: rows d, cols t
    __shared__ char QP[64 * 128];   // Q staging, then Ps[w] = QP + w*2048
    const int tid = threadIdx.x, lane = tid & 63, w = tid >> 6;
    const int bh = blockIdx.x & 127, b = bh >> 4, h = bh & 15;
    const int s0 = (blockIdx.x >> 7) * 64;
    const int g = lane >> 4, qs = lane & 15;

#pragma unroll
    for (int p = 0; p < 2; ++p) {   // Q stage (once)
        int ci = p * 256 + tid;
        int row = ci >> 3, c = (ci & 7) ^ (row & 7);
        gload_lds16(qkv + ((size_t)(s0 + row) * BATCH + b) * 3072 + h * 64 + c * 8,
                    QP + (p * 256 + w * 64) * 16);
    }
    __syncthreads();                // drains vmcnt: Q fully in LDS

    short8 qa0 = *(const short8*)(QP + swz(w * 16 + qs, 0 * 4 + g));
    short8 qa1 = *(const short8*)(QP + swz(w * 16 + qs, 1 * 4 + g));
    asm volatile("s_waitcnt lgkmcnt(0)" ::: "memory");
    __builtin_amdgcn_sched_barrier(0);          // reads complete before P overwrites
    char* Ps = QP + w * 2048;                   // alias: per-wave P scratch

    const short ONEB = (short)0x3F80;           // bf16 1.0
    const short8 ones = {ONEB, ONEB, ONEB, ONEB, ONEB, ONEB, ONEB, ONEB};

    float4v O[5];   // O[0..3] = output cols; O[4] = P-rowsum (ones column)
#pragma unroll
    for (int df = 0; df < 5; ++df) O[df] = (float4v){0.f, 0.f, 0.f, 0.f};
    float m_s = -1e30f;

    for (int t0 = 0; t0 < S_LEN; t0 += 64) {
        __syncthreads();
#pragma unroll
        for (int p = 0; p < 2; ++p) {
            int ci = p * 256 + tid;
            int row = ci >> 3, c = (ci & 7) ^ (row & 7);
            gload_lds16(qkv + ((size_t)(t0 + row) * BATCH + b) * 3072 + EMB + h * 64 + c * 8,
                        Ks + (p * 256 + w * 64) * 16);
            gload_lds16(vt + ((size_t)bh * 64 + row) * S_LEN + t0 + c * 8,
                        Vs + (p * 256 + w * 64) * 16);
        }
        __syncthreads();

        float4v Sf[4];
#pragma unroll
        for (int tf = 0; tf < 4; ++tf) Sf[tf] = (float4v){0.f, 0.f, 0.f, 0.f};
#pragma unroll
        for (int tf = 0; tf < 4; ++tf) {
            int kr = tf * 16 + qs;
            short8 kb0 = *(const short8*)(Ks + swz(kr, 0 * 4 + g));
            short8 kb1 = *(const short8*)(Ks + swz(kr, 1 * 4 + g));
            Sf[tf] = __builtin_amdgcn_mfma_f32_16x16x32_bf16(kb0, qa0, Sf[tf], 0, 0, 0);
            Sf[tf] = __builtin_amdgcn_mfma_f32_16x16x32_bf16(kb1, qa1, Sf[tf], 0, 0, 0);
        }

        float mx = fmaxf(fmaxf(Sf[0][0], Sf[0][1]), fmaxf(Sf[0][2], Sf[0][3]));
#pragma unroll
        for (int tf = 1; tf < 4; ++tf)
            mx = fmaxf(mx, fmaxf(fmaxf(Sf[tf][0], Sf[tf][1]),
                                 fmaxf(Sf[tf][2], Sf[tf][3])));
        mx = fmaxf(mx, __shfl_xor(mx, 16));
        mx = fmaxf(mx, __shfl_xor(mx, 32));

        // defer-max: only rescale when some row grew past THR=8 (P <= 2^8)
        if (!__all(mx - m_s <= 8.0f)) {
            float mnew = fmaxf(m_s, mx);
            float alpha = exp2v(m_s - mnew);
            m_s = mnew;
#pragma unroll
            for (int r = 0; r < 4; ++r) {
                float ar = __shfl(alpha, 4 * g + r);   // alpha for O-row 4g+r
#pragma unroll
                for (int df = 0; df < 5; ++df) O[df][r] *= ar;
            }
        }

        // P = exp2(S - m): pack pairs, ds_write_b64 per tf (no scalar row-sum:
        // the ones-column MFMA below accumulates it into O[4])
#pragma unroll
        for (int tf = 0; tf < 4; ++tf) {
            float p0 = exp2v(Sf[tf][0] - m_s);
            float p1 = exp2v(Sf[tf][1] - m_s);
            float p2 = exp2v(Sf[tf][2] - m_s);
            float p3 = exp2v(Sf[tf][3] - m_s);
            uint2 pk = make_uint2(cvtpk_bf16(p0, p1), cvtpk_bf16(p2, p3));
            *(uint2*)(Ps + (qs << 7) +
                      (((2 * tf + (g >> 1)) ^ (qs & 7)) << 4) + ((g & 1) << 3)) = pk;
        }

        asm volatile("s_waitcnt lgkmcnt(0)" ::: "memory");
        __builtin_amdgcn_sched_barrier(0);

        // O += P V ; O[4] += P * ones (row-sum)
#pragma unroll
        for (int mk = 0; mk < 2; ++mk) {
            short8 pa = *(const short8*)(Ps + swz(qs, mk * 4 + g));
#pragma unroll
            for (int df = 0; df < 4; ++df) {
                int vr = df * 16 + qs;
                short8 vb = *(const short8*)(Vs + swz(vr, mk * 4 + g));
                O[df] = __builtin_amdgcn_mfma_f32_16x16x32_bf16(pa, vb, O[df], 0, 0, 0);
            }
            O[4] = __builtin_amdgcn_mfma_f32_16x16x32_bf16(pa, ones, O[4], 0, 0, 0);
        }
    }

    // O[4][r] = denominator for q-row g*4+r (same lane) -- no shfl needed
#pragma unroll
    for (int r = 0; r < 4; ++r) {
        float ir = __builtin_amdgcn_rcpf(O[4][r]);
#pragma unroll
        for (int df = 0; df < 4; ++df) {
            int srow = s0 + w * 16 + g * 4 + r;
            int d    = df * 16 + qs;
            ctx[((size_t)srow * BATCH + b) * EMB + h * 64 + d] = f2bf(O[df][r] * ir);
        }
    }
}

// ---------------------------------------------------------------- LayerNorm (bf16 in)
__global__ __launch_bounds__(256) void ln_ker_b(const unsigned short* __restrict__ yb,
                                                const float* __restrict__ g,
                                                const float* __restrict__ bta,
                                                float* __restrict__ xo,
                                                unsigned short* __restrict__ xb) {
    const int row = blockIdx.x, tid = threadIdx.x, lane = tid & 63, w = tid >> 6;
    us4 yv = ((const us4*)(yb + (size_t)row * EMB))[tid];
    float4 v;
    v.x = bf2f(yv.x); v.y = bf2f(yv.y); v.z = bf2f(yv.z); v.w = bf2f(yv.w);
    float s = v.x + v.y + v.z + v.w;
    float q = v.x * v.x + v.y * v.y + v.z * v.z + v.w * v.w;
#pragma unroll
    for (int m = 1; m < 64; m <<= 1) {
        s += __shfl_xor(s, m);
        q += __shfl_xor(q, m);
    }
    __shared__ float ps[4], pq[4];
    if (lane == 0) { ps[w] = s; pq[w] = q; }
    __syncthreads();
    s = ps[0] + ps[1] + ps[2] + ps[3];
    q = pq[0] + pq[1] + pq[2] + pq[3];
    float mean = s * (1.f / EMB);
    float var  = q * (1.f / EMB) - mean * mean;
    float rstd = rsqrtf(var + 1e-5f);
    float4 gv = ((const float4*)g)[tid];
    float4 bv = ((const float4*)bta)[tid];
    float4 o;
    o.x = (v.x - mean) * rstd * gv.x + bv.x;
    o.y = (v.y - mean) * rstd * gv.y + bv.y;
    o.z = (v.z - mean) * rstd * gv.z + bv.z;
    o.w = (v.w - mean) * rstd * gv.w + bv.w;
    if (xo) ((float4*)(xo + (size_t)row * EMB))[tid] = o;
    if (xb) {
        us4 ob = { f2bf(o.x), f2bf(o.y), f2bf(o.z), f2bf(o.w) };
        ((us4*)(xb + (size_t)row * EMB))[tid] = ob;
    }
}

// ================================================================ host
// ws layout (MB), liveness-verified (r18):
//   wqkvb[0,6) wob[6,8) w1b[8,16) w2b[16,24)   (dead: wqkvb/wob/w1b by FF2)
//   qkvb [24,72)  QKV -> attn
//   srcbf[72,88)  cast -> QKV;  ctxb[72,88) attn -> out-proj (srcbf dead)
//   vtb  [88,104) vtrans -> attn;  ybf1[88,104) out-proj -> LN1 (vtb dead)
//   xbf  [24,40)  LN1 -> FF2 (qkvb dead)
//   hb   [40,104) FF1 -> FF2
//   ybf2 [0,16)   FF2 -> LN2 (dead weights)
extern "C" void kernel_launch(void* const* d_in, const int* in_sizes, int n_in,
                              void* d_out, int out_size, void* d_ws, size_t ws_size,
                              hipStream_t stream) {
    (void)in_sizes; (void)n_in; (void)out_size;
    const float* src       = (const float*)d_in[0];
    const float* in_proj_w = (const float*)d_in[1];
    const float* in_proj_b = (const float*)d_in[2];
    const float* out_w     = (const float*)d_in[3];
    const float* out_b     = (const float*)d_in[4];
    const float* ln1_g     = (const float*)d_in[5];
    const float* ln1_b     = (const float*)d_in[6];
    const float* ln2_g     = (const float*)d_in[7];
    const float* ln2_b     = (const float*)d_in[8];
    const float* w1        = (const float*)d_in[9];
    const float* b1        = (const float*)d_in[10];
    const float* w2        = (const float*)d_in[11];
    const float* b2        = (const float*)d_in[12];

    const size_t MB = 1u << 20;
    if (ws_size < 104 * MB) return;

    char* ws = (char*)d_ws;
    unsigned short* wqkvb = (unsigned short*)(ws);
    unsigned short* wob   = (unsigned short*)(ws + 6 * MB);
    unsigned short* w1b   = (unsigned short*)(ws + 8 * MB);
    unsigned short* w2b   = (unsigned short*)(ws + 16 * MB);
    unsigned short* qkvb  = (unsigned short*)(ws + 24 * MB);
    unsigned short* srcbf = (unsigned short*)(ws + 72 * MB);
    unsigned short* vtb   = (unsigned short*)(ws + 88 * MB);
    unsigned short* ctxb  = (unsigned short*)(ws + 72 * MB);   // reuse srcbf
    unsigned short* ybf1  = (unsigned short*)(ws + 88 * MB);   // reuse vtb
    unsigned short* xbf   = (unsigned short*)(ws + 24 * MB);   // reuse qkvb
    unsigned short* hb    = (unsigned short*)(ws + 40 * MB);   // reuse rest
    unsigned short* ybf2  = (unsigned short*)(ws);             // reuse dead weights

    // fused cast: src, in_proj_w, out_w, w1, w2 (counts in float4 units)
    const int c0 = ROWS * EMB / 4;
    const int c1 = 3 * EMB * EMB / 4;
    const int c2 = EMB * EMB / 4;
    const int c3 = FFD * EMB / 4;
    const int c4 = EMB * FFD / 4;
    const int ctot = c0 + c1 + c2 + c3 + c4;
    cast_all<<<ctot / 256, 256, 0, stream>>>(
        src, srcbf, c0, in_proj_w, wqkvb, c1, out_w, wob, c2,
        w1, w1b, c3, w2, w2b, c4);

    // QKV projection (1-barrier 256x192, 512 blocks = 2 even rounds)
    gemm256q<<<(3 * EMB / 192) * 32, 512, 0, stream>>>(
        srcbf, wqkvb, in_proj_b, qkvb, ROWS, 3 * EMB, EMB);

    vtrans<<<dim3(S_LEN / 64, BATCH * NH), 256, 0, stream>>>(qkvb, vtb);

    attn<<<(S_LEN / 64) * BATCH * NH, 256, 0, stream>>>(qkvb, vtb, ctxb);

    // out-projection + fp32 src residual -> y1 (bf16), 256x128 1-barrier
    gemm256n<4><<<(EMB / 128) * 32, 512, 0, stream>>>(
        ctxb, wob, out_b, src, nullptr, ybf1, ROWS, EMB, EMB);

    // LN1 (bf16 in) -> xbf
    ln_ker_b<<<ROWS, 256, 0, stream>>>(ybf1, ln1_g, ln1_b, nullptr, xbf);

    // FF1 + ReLU (1-barrier 256², XCD-swizzled)
    gemm256d<2><<<(FFD / 256) * 32, 512, 0, stream>>>(
        xbf, w1b, b1, hb, ROWS, FFD, EMB);

    // FF2 + bf16 x residual -> y2 (bf16), 256x128 1-barrier, XCD-swizzled
    gemm256n<5><<<(EMB / 128) * 32, 512, 0, stream>>>(
        hb, w2b, b2, nullptr, xbf, ybf2, ROWS, EMB, FFD);

    // LN2 (bf16 in) -> fp32 d_out
    ln_ker_b<<<ROWS, 256, 0, stream>>>(ybf2, ln2_g, ln2_b, (float*)d_out, nullptr);
}